// Round 8
// baseline (428.785 us; speedup 1.0000x reference)
//
#include <hip/hip_runtime.h>
#include <math.h>

#define BATCH 64
#define SLATES 25
#define KPS 20
#define EDIM 256
#define DDIM 512
#define HEADS 8
#define HD 64
#define LFULL 501
#define NROWS 500
#define MTOT (BATCH*NROWS)   // 32000
#define CMAX 512             // compacted key capacity
#define NQKV 1536            // packed q|k|v output dim

typedef __attribute__((ext_vector_type(8))) short short8;
typedef __attribute__((ext_vector_type(4))) float f32x4;

__device__ __forceinline__ unsigned short f2bf(float x) {
    unsigned int u = __builtin_bit_cast(unsigned int, x);
    u = (u + 0x7FFFu + ((u >> 16) & 1u)) >> 16;
    return (unsigned short)u;
}
__device__ __forceinline__ float bf2f(unsigned short s) {
    unsigned int u = ((unsigned int)s) << 16;
    return __builtin_bit_cast(float, u);
}
__device__ __forceinline__ float gelu_exact(float x) {
    return 0.5f * x * (1.0f + erff(x * 0.70710678118654752440f));
}

// ---------------------------------------------------------------------------
// fp32 -> bf16 converts / weight packing
// ---------------------------------------------------------------------------
__global__ __launch_bounds__(256) void cvt_kernel(
    const float* __restrict__ src, unsigned short* __restrict__ dst, int n4)
{
    const int i = blockIdx.x * 256 + threadIdx.x;
    if (i >= n4) return;
    float4 v = ((const float4*)src)[i];
    ushort4 o;
    o.x = f2bf(v.x); o.y = f2bf(v.y); o.z = f2bf(v.z); o.w = f2bf(v.w);
    ((ushort4*)dst)[i] = o;
}

struct Cvt2 { const float* s[2]; unsigned short* d[2]; };
__global__ __launch_bounds__(256) void cvt2_kernel(Cvt2 a, int n4)
{
    const int i = blockIdx.x * 256 + threadIdx.x;
    if (i >= n4) return;
    const int y = blockIdx.y;
    float4 v = ((const float4*)a.s[y])[i];
    ushort4 o;
    o.x = f2bf(v.x); o.y = f2bf(v.y); o.z = f2bf(v.z); o.w = f2bf(v.w);
    ((ushort4*)a.d[y])[i] = o;
}

// Pack [Wq;Wk;Wv][:, 0:256] -> (1536 x 256) bf16
__global__ __launch_bounds__(256) void packqkv_kernel(
    const float* __restrict__ Wq, const float* __restrict__ Wk,
    const float* __restrict__ Wv, unsigned short* __restrict__ dst)
{
    const int y = blockIdx.y;
    const float* W = (y == 0) ? Wq : (y == 1) ? Wk : Wv;
    const int i = blockIdx.x * 256 + threadIdx.x;
    const int row = i >> 6, c4 = (i & 63) * 4;
    float4 v = *(const float4*)&W[(size_t)row * DDIM + c4];
    ushort4 o;
    o.x = f2bf(v.x); o.y = f2bf(v.y); o.z = f2bf(v.z); o.w = f2bf(v.w);
    *(ushort4*)&dst[((size_t)y * DDIM + row) * EDIM + c4] = o;
}

// ---------------------------------------------------------------------------
// Click compaction: one wave per batch.
// ---------------------------------------------------------------------------
__global__ __launch_bounds__(64) void compact_kernel(
    const int* __restrict__ resp, int* __restrict__ cidx, int* __restrict__ cnt)
{
    const int b = blockIdx.x, lane = threadIdx.x;
    int a[8]; int c = 0;
#pragma unroll
    for (int j = 0; j < 8; ++j) {
        const int l = lane * 8 + j;
        int al = 0;
        if (l == 0) al = 1;
        else if (l <= NROWS) al = (resp[(size_t)b * NROWS + l - 1] > 0) ? 1 : 0;
        a[j] = al; c += al;
    }
    int incl = c;
#pragma unroll
    for (int off = 1; off < 64; off <<= 1) {
        int t = __shfl_up(incl, off, 64);
        if (lane >= off) incl += t;
    }
    int run = incl - c;
#pragma unroll
    for (int j = 0; j < 8; ++j) {
        const int l = lane * 8 + j;
        if (l >= 1 && l <= 481 && (l % 20) == 1)
            cnt[b * 32 + (l - 1) / 20] = run;
        cidx[b * 512 + l] = a[j] ? run : -1;
        run += a[j];
    }
}

// ---------------------------------------------------------------------------
// Per-batch user bias tables (packed [B][1536]) + position-0 rows.
// ---------------------------------------------------------------------------
__global__ __launch_bounds__(256) void user_bias_kernel(
    const float* __restrict__ user,
    const float* __restrict__ Wq, const float* __restrict__ bq,
    const float* __restrict__ Wk, const float* __restrict__ bk,
    const float* __restrict__ Wv, const float* __restrict__ bv,
    float* __restrict__ uball,
    unsigned short* __restrict__ qb, unsigned short* __restrict__ kc,
    unsigned short* __restrict__ vc)
{
    const int b = blockIdx.x;
    const int y = blockIdx.y;
    const int tid = threadIdx.x;
    const float* W  = (y == 0) ? Wq : (y == 1) ? Wk : Wv;
    const float* bi = (y == 0) ? bq : (y == 1) ? bk : bv;

    __shared__ float us[EDIM];
    if (tid < EDIM) us[tid] = user[b * EDIM + tid];
    __syncthreads();
    for (int o = tid; o < DDIM; o += 256) {
        float s = bi[o];
        const float* wr = &W[(size_t)o * DDIM + EDIM];
#pragma unroll 4
        for (int e = 0; e < EDIM; ++e) s += us[e] * wr[e];
        uball[(size_t)b * NQKV + y * DDIM + o] = s;
        const int hh = o >> 6, dd = o & 63;
        const size_t bh = (size_t)b * HEADS + hh;
        if (y == 0)      qb[(bh * LFULL) * HD + dd] = f2bf(bi[o]);
        else if (y == 1) kc[(bh * CMAX) * HD + dd] = f2bf(bi[o]);
        else             vc[(bh * HD + dd) * CMAX] = f2bf(bi[o]);
    }
}

// ---------------------------------------------------------------------------
// Direct-fragment GEMM: no LDS, no barriers (attn-style). Each wave owns a
// 64x64 output tile, loads A/W fragments straight from global (W is
// L2-resident; 4 waves per block share the A band -> L1 hits), with a
// register-double-buffered k-loop.
// KD: inner dim (256 or 512). MODE 0: merged QKV epilogue (uball bias, q
// head-major, K/V^T compacted). MODE 1: +bias, fp32 out. MODE 2: +bias,
// gelu, dot W2 -> 8 partials/row.
// ---------------------------------------------------------------------------
template <int KD, int MODE>
__global__ __launch_bounds__(256) void gemm_direct(
    const unsigned short* __restrict__ A,
    const unsigned short* __restrict__ W,
    const float* __restrict__ uball, const int* __restrict__ cidx,
    unsigned short* __restrict__ oq, unsigned short* __restrict__ ok,
    unsigned short* __restrict__ ov,
    const float* __restrict__ bias, void* __restrict__ outp,
    const float* __restrict__ W2, float* __restrict__ part)
{
    const int tid = threadIdx.x;
    const int lane = tid & 63, w = tid >> 6;
    const int n0 = blockIdx.x * 256 + w * 64;   // wave's n window
    const int m0 = blockIdx.y * 64;             // wave's m window
    const int frow = lane & 15, fkk = (lane >> 4) * 8;

    f32x4 acc[4][4];
#pragma unroll
    for (int i = 0; i < 4; ++i)
#pragma unroll
        for (int j = 0; j < 4; ++j) acc[i][j] = (f32x4){0.f, 0.f, 0.f, 0.f};

    const unsigned short* aP[4];
    const unsigned short* wP[4];
#pragma unroll
    for (int i = 0; i < 4; ++i) {
        aP[i] = &A[(size_t)(m0 + i * 16 + frow) * KD + fkk];
        wP[i] = &W[(size_t)(n0 + i * 16 + frow) * KD + fkk];
    }

    short8 aC[4], wC[4], aN[4], wN[4];
#pragma unroll
    for (int i = 0; i < 4; ++i) {
        aC[i] = *(const short8*)(aP[i]);
        wC[i] = *(const short8*)(wP[i]);
    }

    constexpr int NST = KD / 32;   // 8 or 16 (even)
    for (int t = 0; t < NST; t += 2) {
        const int k1 = (t + 1) * 32;
        if (t + 1 < NST) {
#pragma unroll
            for (int i = 0; i < 4; ++i) {
                aN[i] = *(const short8*)(aP[i] + k1);
                wN[i] = *(const short8*)(wP[i] + k1);
            }
        }
#pragma unroll
        for (int mi = 0; mi < 4; ++mi)
#pragma unroll
            for (int ni = 0; ni < 4; ++ni)
                acc[mi][ni] = __builtin_amdgcn_mfma_f32_16x16x32_bf16(
                    aC[mi], wC[ni], acc[mi][ni], 0, 0, 0);
        const int k2 = (t + 2) * 32;
        if (t + 2 < NST) {
#pragma unroll
            for (int i = 0; i < 4; ++i) {
                aC[i] = *(const short8*)(aP[i] + k2);
                wC[i] = *(const short8*)(wP[i] + k2);
            }
        }
#pragma unroll
        for (int mi = 0; mi < 4; ++mi)
#pragma unroll
            for (int ni = 0; ni < 4; ++ni)
                acc[mi][ni] = __builtin_amdgcn_mfma_f32_16x16x32_bf16(
                    aN[mi], wN[ni], acc[mi][ni], 0, 0, 0);
    }

    if (MODE == 0) {
        const int z = n0 >> 9;               // 0=q 1=k 2=v
        const int b0 = m0 / NROWS;           // once per wave
        const int split = (b0 + 1) * NROWS;  // rows >= split belong to b0+1
        const int b1 = (split <= m0 + 63) ? b0 + 1 : b0;
        float ub0[4], ub1[4];
#pragma unroll
        for (int ni = 0; ni < 4; ++ni) {
            const int np = n0 + ni * 16 + frow;
            ub0[ni] = uball[(size_t)b0 * NQKV + np];
            ub1[ni] = uball[(size_t)b1 * NQKV + np];
        }
#pragma unroll
        for (int mi = 0; mi < 4; ++mi) {
#pragma unroll
            for (int r = 0; r < 4; ++r) {
                const int m = m0 + mi * 16 + (lane >> 4) * 4 + r;
                const int hi = (m >= split);
                const int b = hi ? b1 : b0;
                const int l = m - b * NROWS + 1;
                const size_t bh = (size_t)b * HEADS + (n0 >> 6 & 7);
                int c = 0;
                if (z != 0) c = cidx[b * 512 + l];
#pragma unroll
                for (int ni = 0; ni < 4; ++ni) {
                    const int nn = (n0 + ni * 16 + frow) & 511;
                    const int hh = nn >> 6, dd = nn & 63;
                    const size_t bhn = (size_t)b * HEADS + hh;
                    const float v = acc[mi][ni][r] + (hi ? ub1[ni] : ub0[ni]);
                    if (z == 0) {
                        oq[(bhn * LFULL + l) * HD + dd] = f2bf(v);
                    } else if (c >= 0) {
                        if (z == 1) ok[(bhn * CMAX + c) * HD + dd] = f2bf(v);
                        else        ov[(bhn * HD + dd) * CMAX + c] = f2bf(v);
                    }
                }
            }
        }
    } else if (MODE == 1) {
        float bv4[4];
#pragma unroll
        for (int ni = 0; ni < 4; ++ni) bv4[ni] = bias[n0 + ni * 16 + frow];
#pragma unroll
        for (int mi = 0; mi < 4; ++mi)
#pragma unroll
            for (int ni = 0; ni < 4; ++ni) {
                const int n = n0 + ni * 16 + frow;
#pragma unroll
                for (int r = 0; r < 4; ++r) {
                    const int m = m0 + mi * 16 + (lane >> 4) * 4 + r;
                    ((float*)outp)[(size_t)m * DDIM + n] = acc[mi][ni][r] + bv4[ni];
                }
            }
    } else {
        float w2v[4], bv4[4];
#pragma unroll
        for (int ni = 0; ni < 4; ++ni) {
            const int n = n0 + ni * 16 + frow;
            w2v[ni] = W2[n];
            bv4[ni] = bias[n];
        }
        float ps[4][4];
#pragma unroll
        for (int mi = 0; mi < 4; ++mi)
#pragma unroll
            for (int r = 0; r < 4; ++r) ps[mi][r] = 0.f;
#pragma unroll
        for (int mi = 0; mi < 4; ++mi)
#pragma unroll
            for (int ni = 0; ni < 4; ++ni)
#pragma unroll
                for (int r = 0; r < 4; ++r)
                    ps[mi][r] += gelu_exact(acc[mi][ni][r] + bv4[ni]) * w2v[ni];
        const int slot = n0 >> 6;   // 0..7
#pragma unroll
        for (int mi = 0; mi < 4; ++mi)
#pragma unroll
            for (int r = 0; r < 4; ++r) {
                float s = ps[mi][r];
                s += __shfl_xor(s, 1, 64);
                s += __shfl_xor(s, 2, 64);
                s += __shfl_xor(s, 4, 64);
                s += __shfl_xor(s, 8, 64);
                if (frow == 0) {
                    const int m = m0 + mi * 16 + (lane >> 4) * 4 + r;
                    part[(size_t)m * 8 + slot] = s;
                }
            }
    }
}

// ---------------------------------------------------------------------------
// Final reduction: out[m] = b2 + sum of 8 partials.
// ---------------------------------------------------------------------------
__global__ __launch_bounds__(256) void w2red_kernel(
    const float* __restrict__ part, const float* __restrict__ b2,
    float* __restrict__ out)
{
    const int m = blockIdx.x * 256 + threadIdx.x;
    if (m >= MTOT) return;
    const float* p = part + (size_t)m * 8;
    float s = b2[0];
#pragma unroll
    for (int i = 0; i < 8; ++i) s += p[i];
    out[m] = s;
}

// ---------------------------------------------------------------------------
// Attention (unchanged): compacted keys, bf16 score LDS, barrier-free loops.
// ---------------------------------------------------------------------------
__global__ __launch_bounds__(256) void attn_mfma(
    const unsigned short* __restrict__ qx, const unsigned short* __restrict__ kc,
    const unsigned short* __restrict__ vc, const int* __restrict__ cnt,
    unsigned short* __restrict__ outb)
{
    const int s0 = blockIdx.x, h = blockIdx.y, b = blockIdx.z;
    const int tid = threadIdx.x, lane = tid & 63, w = tid >> 6;
    const int nck = cnt[b * 32 + s0];
    const int NT = (nck + 63) >> 6;
    const int NK = NT << 6;

    __shared__ __align__(16) unsigned short scb[KPS][520];
    __shared__ float invb[KPS];

    const int frow = lane & 15, fk = (lane >> 4) * 8;
    const size_t bh = (size_t)b * HEADS + h;
    const unsigned short* kbase = kc + bh * (CMAX * HD);
    const unsigned short* vbase = vc + bh * (HD * CMAX);

    short8 qf[2][2];
#pragma unroll
    for (int mi = 0; mi < 2; ++mi) {
        const int qrow = mi * 16 + frow;
#pragma unroll
        for (int ks = 0; ks < 2; ++ks) {
            short8 v = {};
            if (qrow < KPS)
                v = *(const short8*)&qx[(bh * LFULL + s0 * KPS + 1 + qrow) * HD
                                        + ks * 32 + fk];
            qf[mi][ks] = v;
        }
    }

    for (int t = 0; t < NT; ++t) {
        const int key = (t << 6) + w * 16 + frow;
        const unsigned short* kr = kbase + (size_t)key * HD;
        const short8 kf0 = *(const short8*)(kr + fk);
        const short8 kf1 = *(const short8*)(kr + 32 + fk);
        f32x4 s2[2];
#pragma unroll
        for (int mi = 0; mi < 2; ++mi) {
            s2[mi] = (f32x4){0.f, 0.f, 0.f, 0.f};
            s2[mi] = __builtin_amdgcn_mfma_f32_16x16x32_bf16(qf[mi][0], kf0, s2[mi], 0, 0, 0);
            s2[mi] = __builtin_amdgcn_mfma_f32_16x16x32_bf16(qf[mi][1], kf1, s2[mi], 0, 0, 0);
        }
        const bool allow = key < nck;
#pragma unroll
        for (int mi = 0; mi < 2; ++mi)
#pragma unroll
            for (int r = 0; r < 4; ++r) {
                const int row = mi * 16 + (lane >> 4) * 4 + r;
                if (row < KPS)
                    scb[row][key] = f2bf(allow ? s2[mi][r] * 0.125f : -1e30f);
            }
    }
    __syncthreads();

    for (int r = w; r < KPS; r += 4) {
        float xv[8];
        float mx = -1e30f;
#pragma unroll
        for (int i = 0; i < 8; ++i) {
            const int k_ = lane + i * 64;
            if (k_ < NK) { xv[i] = bf2f(scb[r][k_]); mx = fmaxf(mx, xv[i]); }
        }
#pragma unroll
        for (int off = 32; off; off >>= 1) mx = fmaxf(mx, __shfl_xor(mx, off, 64));
        float ss = 0.f;
#pragma unroll
        for (int i = 0; i < 8; ++i) {
            const int k_ = lane + i * 64;
            if (k_ < NK) {
                const float p = __expf(xv[i] - mx);
                ss += p;
                scb[r][k_] = f2bf(p);
            }
        }
#pragma unroll
        for (int off = 32; off; off >>= 1) ss += __shfl_xor(ss, off, 64);
        if (lane == 0) invb[r] = 1.0f / ss;
    }
    __syncthreads();

    f32x4 po[2];
    po[0] = (f32x4){0.f, 0.f, 0.f, 0.f};
    po[1] = (f32x4){0.f, 0.f, 0.f, 0.f};
    const unsigned short* vrow = vbase + (size_t)(w * 16 + frow) * CMAX;
    for (int t = 0; t < NT; ++t) {
#pragma unroll
        for (int ks = 0; ks < 2; ++ks) {
            const int kb0 = (t << 6) + ks * 32 + fk;
            short8 vf;
            if (t + 1 < NT) {
                vf = *(const short8*)(vrow + kb0);
            } else if (kb0 + 8 <= nck) {
                vf = *(const short8*)(vrow + kb0);
            } else {
#pragma unroll
                for (int j = 0; j < 8; ++j)
                    vf[j] = (kb0 + j < nck) ? (short)vrow[kb0 + j] : (short)0;
            }
#pragma unroll
            for (int mi = 0; mi < 2; ++mi) {
                short8 pf = {};
                const int prow = mi * 16 + frow;
                if (prow < KPS)
                    pf = *(const short8*)&scb[prow][kb0];
                po[mi] = __builtin_amdgcn_mfma_f32_16x16x32_bf16(pf, vf, po[mi], 0, 0, 0);
            }
        }
    }

#pragma unroll
    for (int mi = 0; mi < 2; ++mi)
#pragma unroll
        for (int r = 0; r < 4; ++r) {
            const int row = mi * 16 + (lane >> 4) * 4 + r;
            if (row < KPS)
                outb[((size_t)b * NROWS + s0 * KPS + row) * DDIM
                     + h * HD + w * 16 + frow] = f2bf(po[mi][r] * invb[row]);
        }
}

// ---------------------------------------------------------------------------
// LayerNorm fp32 -> bf16.
// ---------------------------------------------------------------------------
__global__ __launch_bounds__(256) void ln_kernel(
    const float* __restrict__ f, const float* __restrict__ g,
    const float* __restrict__ bt, unsigned short* __restrict__ o)
{
    const int row = blockIdx.x * 4 + (threadIdx.x >> 6);
    const int lane = threadIdx.x & 63;
    const float* fr = f + (size_t)row * DDIM;
    float xv[8];
    float s = 0.f;
#pragma unroll
    for (int i = 0; i < 8; ++i) { xv[i] = fr[lane + i * 64]; s += xv[i]; }
#pragma unroll
    for (int off = 32; off; off >>= 1) s += __shfl_xor(s, off, 64);
    const float mu = s * (1.0f / DDIM);
    float var = 0.f;
#pragma unroll
    for (int i = 0; i < 8; ++i) { const float d0 = xv[i] - mu; var += d0 * d0; }
#pragma unroll
    for (int off = 32; off; off >>= 1) var += __shfl_xor(var, off, 64);
    const float rs = rsqrtf(var * (1.0f / DDIM) + 1e-5f);
#pragma unroll
    for (int i = 0; i < 8; ++i) {
        const int d0 = lane + i * 64;
        o[(size_t)row * DDIM + d0] = f2bf((xv[i] - mu) * rs * g[d0] + bt[d0]);
    }
}

// ---------------------------------------------------------------------------
extern "C" void kernel_launch(void* const* d_in, const int* in_sizes, int n_in,
                              void* d_out, int out_size, void* d_ws, size_t ws_size,
                              hipStream_t stream)
{
    const float* item = (const float*)d_in[0];
    const float* user = (const float*)d_in[1];
    const int*   resp = (const int*)d_in[2];
    const float* Wq = (const float*)d_in[3];  const float* bq = (const float*)d_in[4];
    const float* Wk = (const float*)d_in[5];  const float* bk = (const float*)d_in[6];
    const float* Wv = (const float*)d_in[7];  const float* bv = (const float*)d_in[8];
    const float* Wo = (const float*)d_in[9];  const float* bo = (const float*)d_in[10];
    const float* lng = (const float*)d_in[11]; const float* lnb = (const float*)d_in[12];
    const float* W1 = (const float*)d_in[13]; const float* b1 = (const float*)d_in[14];
    const float* W2 = (const float*)d_in[15]; const float* b2 = (const float*)d_in[16];
    float* out = (float*)d_out;

    char* p = (char*)d_ws;
    auto alloc = [&](size_t bytes) { char* r = p; p += (bytes + 255) & ~(size_t)255; return r; };
    const size_t NITEM = (size_t)BATCH * NROWS * EDIM;
    const size_t NW    = (size_t)DDIM * DDIM;
    const size_t NQ    = (size_t)BATCH * HEADS * LFULL * HD;
    const size_t NC    = (size_t)BATCH * HEADS * CMAX * HD;
    const size_t NMD   = (size_t)MTOT * DDIM;
    const size_t PAD   = 8192;

    unsigned short* itemb  = (unsigned short*)alloc(NITEM * 2);
    unsigned short* Wqkvb  = (unsigned short*)alloc((size_t)NQKV * EDIM * 2);
    unsigned short* Wob    = (unsigned short*)alloc(NW * 2);
    unsigned short* W1b    = (unsigned short*)alloc(NW * 2);
    unsigned short* qb     = (unsigned short*)alloc(NQ * 2 + PAD);
    unsigned short* kcb    = (unsigned short*)alloc(NC * 2 + PAD);
    unsigned short* vcb    = (unsigned short*)alloc(NC * 2 + PAD);
    unsigned short* aob    = (unsigned short*)alloc(NMD * 2);
    float* fbuf  = (float*)alloc(NMD * 4);
    float* uball = (float*)alloc((size_t)BATCH * NQKV * 4);
    float* part  = (float*)alloc((size_t)MTOT * 8 * 4);
    int* cidx    = (int*)alloc((size_t)BATCH * 512 * 4);
    int* cnt     = (int*)alloc((size_t)BATCH * 32 * 4);

    cvt_kernel<<<dim3((NITEM / 4 + 255) / 256), 256, 0, stream>>>(item, itemb, NITEM / 4);
    packqkv_kernel<<<dim3(DDIM * EDIM / 4 / 256, 3), 256, 0, stream>>>(Wq, Wk, Wv, Wqkvb);
    Cvt2 c2;
    c2.s[0] = Wo; c2.s[1] = W1; c2.d[0] = Wob; c2.d[1] = W1b;
    cvt2_kernel<<<dim3(NW / 4 / 256, 2), 256, 0, stream>>>(c2, NW / 4);

    compact_kernel<<<dim3(BATCH), 64, 0, stream>>>(resp, cidx, cnt);

    user_bias_kernel<<<dim3(BATCH, 3), 256, 0, stream>>>(
        user, Wq, bq, Wk, bk, Wv, bv, uball, qb, kcb, vcb);

    // QKV: M=32000, N=1536, K=256
    gemm_direct<EDIM, 0><<<dim3(NQKV / 256, MTOT / 64), 256, 0, stream>>>(
        itemb, Wqkvb, uball, cidx, qb, kcb, vcb, nullptr, nullptr, nullptr, nullptr);

    attn_mfma<<<dim3(SLATES, HEADS, BATCH), 256, 0, stream>>>(qb, kcb, vcb, cnt, aob);

    // f = ao @ Wo^T + bo (fp32)
    gemm_direct<DDIM, 1><<<dim3(DDIM / 256, MTOT / 64), 256, 0, stream>>>(
        aob, Wob, nullptr, nullptr, nullptr, nullptr, nullptr, bo, fbuf, nullptr, nullptr);
    ln_kernel<<<dim3(MTOT / 4), 256, 0, stream>>>(fbuf, lng, lnb, aob);
    // h = gelu(ln @ W1^T + b1) . W2 partials
    gemm_direct<DDIM, 2><<<dim3(DDIM / 256, MTOT / 64), 256, 0, stream>>>(
        aob, W1b, nullptr, nullptr, nullptr, nullptr, nullptr, b1, nullptr, W2, part);
    w2red_kernel<<<dim3((MTOT + 255) / 256), 256, 0, stream>>>(part, b2, out);
}

// Round 9
// 305.601 us; speedup vs baseline: 1.4031x; 1.4031x over previous
//
#include <hip/hip_runtime.h>
#include <math.h>

#define BATCH 64
#define SLATES 25
#define KPS 20
#define EDIM 256
#define DDIM 512
#define HEADS 8
#define HD 64
#define LFULL 501
#define NROWS 500
#define MTOT (BATCH*NROWS)   // 32000
#define CMAX 512             // compacted key capacity
#define NQKV 1536            // packed q|k|v output dim

typedef __attribute__((ext_vector_type(8))) short short8;
typedef __attribute__((ext_vector_type(4))) float f32x4;

__device__ __forceinline__ unsigned short f2bf(float x) {
    unsigned int u = __builtin_bit_cast(unsigned int, x);
    u = (u + 0x7FFFu + ((u >> 16) & 1u)) >> 16;
    return (unsigned short)u;
}
__device__ __forceinline__ float bf2f(unsigned short s) {
    unsigned int u = ((unsigned int)s) << 16;
    return __builtin_bit_cast(float, u);
}
__device__ __forceinline__ float gelu_exact(float x) {
    return 0.5f * x * (1.0f + erff(x * 0.70710678118654752440f));
}
__device__ __forceinline__ void gload16(const void* g, void* l) {
    __builtin_amdgcn_global_load_lds(
        (const __attribute__((address_space(1))) void*)g,
        (__attribute__((address_space(3))) void*)l, 16, 0, 0);
}

// ---------------------------------------------------------------------------
// fp32 -> bf16 converts / weight packing
// ---------------------------------------------------------------------------
__global__ __launch_bounds__(256) void cvt_kernel(
    const float* __restrict__ src, unsigned short* __restrict__ dst, int n4)
{
    const int i = blockIdx.x * 256 + threadIdx.x;
    if (i >= n4) return;
    float4 v = ((const float4*)src)[i];
    ushort4 o;
    o.x = f2bf(v.x); o.y = f2bf(v.y); o.z = f2bf(v.z); o.w = f2bf(v.w);
    ((ushort4*)dst)[i] = o;
}

struct Cvt2 { const float* s[2]; unsigned short* d[2]; };
__global__ __launch_bounds__(256) void cvt2_kernel(Cvt2 a, int n4)
{
    const int i = blockIdx.x * 256 + threadIdx.x;
    if (i >= n4) return;
    const int y = blockIdx.y;
    float4 v = ((const float4*)a.s[y])[i];
    ushort4 o;
    o.x = f2bf(v.x); o.y = f2bf(v.y); o.z = f2bf(v.z); o.w = f2bf(v.w);
    ((ushort4*)a.d[y])[i] = o;
}

// Pack [Wq;Wk;Wv][:, 0:256] -> (1536 x 256) bf16
__global__ __launch_bounds__(256) void packqkv_kernel(
    const float* __restrict__ Wq, const float* __restrict__ Wk,
    const float* __restrict__ Wv, unsigned short* __restrict__ dst)
{
    const int y = blockIdx.y;
    const float* W = (y == 0) ? Wq : (y == 1) ? Wk : Wv;
    const int i = blockIdx.x * 256 + threadIdx.x;
    const int row = i >> 6, c4 = (i & 63) * 4;
    float4 v = *(const float4*)&W[(size_t)row * DDIM + c4];
    ushort4 o;
    o.x = f2bf(v.x); o.y = f2bf(v.y); o.z = f2bf(v.z); o.w = f2bf(v.w);
    *(ushort4*)&dst[((size_t)y * DDIM + row) * EDIM + c4] = o;
}

// ---------------------------------------------------------------------------
// Click compaction: one wave per batch.
// ---------------------------------------------------------------------------
__global__ __launch_bounds__(64) void compact_kernel(
    const int* __restrict__ resp, int* __restrict__ cidx, int* __restrict__ cnt)
{
    const int b = blockIdx.x, lane = threadIdx.x;
    int a[8]; int c = 0;
#pragma unroll
    for (int j = 0; j < 8; ++j) {
        const int l = lane * 8 + j;
        int al = 0;
        if (l == 0) al = 1;
        else if (l <= NROWS) al = (resp[(size_t)b * NROWS + l - 1] > 0) ? 1 : 0;
        a[j] = al; c += al;
    }
    int incl = c;
#pragma unroll
    for (int off = 1; off < 64; off <<= 1) {
        int t = __shfl_up(incl, off, 64);
        if (lane >= off) incl += t;
    }
    int run = incl - c;
#pragma unroll
    for (int j = 0; j < 8; ++j) {
        const int l = lane * 8 + j;
        if (l >= 1 && l <= 481 && (l % 20) == 1)
            cnt[b * 32 + (l - 1) / 20] = run;
        cidx[b * 512 + l] = a[j] ? run : -1;
        run += a[j];
    }
}

// ---------------------------------------------------------------------------
// Per-batch user bias tables (packed [B][1536]) + position-0 rows.
// ---------------------------------------------------------------------------
__global__ __launch_bounds__(256) void user_bias_kernel(
    const float* __restrict__ user,
    const float* __restrict__ Wq, const float* __restrict__ bq,
    const float* __restrict__ Wk, const float* __restrict__ bk,
    const float* __restrict__ Wv, const float* __restrict__ bv,
    float* __restrict__ uball,
    unsigned short* __restrict__ qb, unsigned short* __restrict__ kc,
    unsigned short* __restrict__ vc)
{
    const int b = blockIdx.x;
    const int y = blockIdx.y;
    const int tid = threadIdx.x;
    const float* W  = (y == 0) ? Wq : (y == 1) ? Wk : Wv;
    const float* bi = (y == 0) ? bq : (y == 1) ? bk : bv;

    __shared__ float us[EDIM];
    if (tid < EDIM) us[tid] = user[b * EDIM + tid];
    __syncthreads();
    for (int o = tid; o < DDIM; o += 256) {
        float s = bi[o];
        const float* wr = &W[(size_t)o * DDIM + EDIM];
#pragma unroll 4
        for (int e = 0; e < EDIM; ++e) s += us[e] * wr[e];
        uball[(size_t)b * NQKV + y * DDIM + o] = s;
        const int hh = o >> 6, dd = o & 63;
        const size_t bh = (size_t)b * HEADS + hh;
        if (y == 0)      qb[(bh * LFULL) * HD + dd] = f2bf(bi[o]);
        else if (y == 1) kc[(bh * CMAX) * HD + dd] = f2bf(bi[o]);
        else             vc[(bh * HD + dd) * CMAX] = f2bf(bi[o]);
    }
}

// ---------------------------------------------------------------------------
// Merged QKV GEMM: counted-vmcnt 3-buffer pipeline + LDS-bounce coalesced
// epilogue + XCD-chunked block swizzle. Grid = (12, 250) = 3000 blocks.
// ---------------------------------------------------------------------------
__global__ __launch_bounds__(256) void gemm_qkv(
    const unsigned short* __restrict__ A,
    const unsigned short* __restrict__ Wqkv,
    const float* __restrict__ uball, const int* __restrict__ cidx,
    unsigned short* __restrict__ oq, unsigned short* __restrict__ ok,
    unsigned short* __restrict__ ov)
{
    const int tid = threadIdx.x;
    // XCD-chunked bijective swizzle: 3000 blocks = 8 XCDs x 375
    const int lin = blockIdx.y * gridDim.x + blockIdx.x;
    const int vb  = (lin & 7) * 375 + (lin >> 3);
    const int n0 = (vb % 12) * 128;   // 0..1535
    const int m0 = (vb / 12) * 128;
    const int lane = tid & 63, wid = tid >> 6;
    const int wm = (wid & 1) * 64, wn = (wid >> 1) * 64;

    // 49152 B staging, reused as 128x136 bounce tile (34816 B) in epilogue
    __shared__ __align__(16) unsigned short sm[24576];
    __shared__ int cids[128];
    auto As = [&](int buf) { return (unsigned short(*)[32])(sm + buf * 4096); };
    auto Ws = [&](int buf) { return (unsigned short(*)[32])(sm + 12288 + buf * 4096); };
    auto bounce = (unsigned short(*)[136])sm;

    f32x4 acc[4][4];
#pragma unroll
    for (int i = 0; i < 4; ++i)
#pragma unroll
        for (int j = 0; j < 4; ++j) acc[i][j] = (f32x4){0.f, 0.f, 0.f, 0.f};

    const unsigned short* gA0 = &A[(size_t)(m0 + wid * 16 + (lane >> 2)) * EDIM + (lane & 3) * 8];
    const unsigned short* gA1 = gA0 + (size_t)64 * EDIM;
    const unsigned short* gW0 = &Wqkv[(size_t)(n0 + wid * 16 + (lane >> 2)) * EDIM + (lane & 3) * 8];
    const unsigned short* gW1 = gW0 + (size_t)64 * EDIM;
    const int frow = lane & 15, fk = (lane >> 4) * 8;

    auto stage = [&](int buf, int k0) {
        gload16(gA0 + k0, &As(buf)[wid * 16][0]);
        gload16(gA1 + k0, &As(buf)[64 + wid * 16][0]);
        gload16(gW0 + k0, &Ws(buf)[wid * 16][0]);
        gload16(gW1 + k0, &Ws(buf)[64 + wid * 16][0]);
    };
    stage(0, 0);
    stage(1, 32);

    const int nst = EDIM / 32;   // 8
    for (int t = 0; t < nst; ++t) {
        const int cur = t % 3;
        if (t < nst - 1) asm volatile("s_waitcnt vmcnt(4)" ::: "memory");
        else             asm volatile("s_waitcnt vmcnt(0)" ::: "memory");
        __builtin_amdgcn_s_barrier();
        __builtin_amdgcn_sched_barrier(0);
        short8 af[4], wf[4];
#pragma unroll
        for (int mi = 0; mi < 4; ++mi)
            af[mi] = *(const short8*)&As(cur)[wm + mi * 16 + frow][fk];
#pragma unroll
        for (int ni = 0; ni < 4; ++ni)
            wf[ni] = *(const short8*)&Ws(cur)[wn + ni * 16 + frow][fk];
#pragma unroll
        for (int mi = 0; mi < 4; ++mi)
#pragma unroll
            for (int ni = 0; ni < 4; ++ni)
                acc[mi][ni] = __builtin_amdgcn_mfma_f32_16x16x32_bf16(
                    af[mi], wf[ni], acc[mi][ni], 0, 0, 0);
        if (t + 2 < nst) stage((t + 2) % 3, (t + 2) * 32);
    }

    // ---- epilogue: bounce through LDS for coalesced stores ----
    const int z = n0 >> 9;               // 0=q 1=k 2=v
    const int b0 = m0 / NROWS;
    const int split = (b0 + 1) * NROWS;
    const int b1 = (split <= m0 + 127) ? b0 + 1 : b0;
    float ub0[4], ub1[4];
#pragma unroll
    for (int ni = 0; ni < 4; ++ni) {
        const int np = n0 + wn + ni * 16 + frow;
        ub0[ni] = uball[(size_t)b0 * NQKV + np];
        ub1[ni] = uball[(size_t)b1 * NQKV + np];
    }
    __syncthreads();   // staging LDS reads fully retired
    if (z != 0 && tid < 128) {
        const int m = m0 + tid;
        const int b = (m >= split) ? b1 : b0;
        cids[tid] = cidx[b * 512 + (m - b * NROWS + 1)];
    }
#pragma unroll
    for (int mi = 0; mi < 4; ++mi)
#pragma unroll
        for (int r = 0; r < 4; ++r) {
            const int ml = wm + mi * 16 + (lane >> 4) * 4 + r;
            const bool hi = (m0 + ml >= split);
#pragma unroll
            for (int ni = 0; ni < 4; ++ni)
                bounce[ml][wn + ni * 16 + frow] =
                    f2bf(acc[mi][ni][r] + (hi ? ub1[ni] : ub0[ni]));
        }
    __syncthreads();

    const int h0 = (n0 & 511) >> 6;      // block covers heads h0, h0+1
    if (z == 0) {
        const int row = tid >> 1, half = tid & 1;
        const int m = m0 + row;
        const int b = (m >= split) ? b1 : b0;
        const int l = m - b * NROWS + 1;
        unsigned short* dst = &oq[(((size_t)b * HEADS + h0 + half) * LFULL + l) * HD];
        const unsigned short* src = &bounce[row][half * 64];
#pragma unroll
        for (int j = 0; j < 8; ++j)
            *(uint4*)(dst + j * 8) = *(const uint4*)(src + j * 8);
    } else if (z == 1) {
        const int row = tid >> 1, half = tid & 1;
        const int c = cids[row];
        if (c >= 0) {
            const int m = m0 + row;
            const int b = (m >= split) ? b1 : b0;
            unsigned short* dst = &ok[(((size_t)b * HEADS + h0 + half) * CMAX + c) * HD];
            const unsigned short* src = &bounce[row][half * 64];
#pragma unroll
            for (int j = 0; j < 8; ++j)
                *(uint4*)(dst + j * 8) = *(const uint4*)(src + j * 8);
        }
    } else {
        const int col = tid & 127, mh = tid >> 7;
        const int hh = h0 + (col >> 6), dd = col & 63;
        for (int mm = 0; mm < 64; ++mm) {
            const int row = mh * 64 + mm;
            const int c = cids[row];
            if (c >= 0) {
                const int m = m0 + row;
                const int b = (m >= split) ? b1 : b0;
                ov[((size_t)b * HEADS + hh) * (size_t)(HD * CMAX)
                   + (size_t)dd * CMAX + c] = bounce[row][col];
            }
        }
    }
}

// ---------------------------------------------------------------------------
// Generic bf16 GEMM (counted-vmcnt 3-buffer) + XCD swizzle (1000 = 8 x 125).
// MODE 1: +bias, bf16 out. MODE 2: +bias, gelu, dot W2 -> 8 partials/row.
// ---------------------------------------------------------------------------
template <int MODE>
__global__ __launch_bounds__(256) void gemm_bf16(
    const unsigned short* __restrict__ A,
    const unsigned short* __restrict__ W,
    const float* __restrict__ bias, void* __restrict__ outp,
    const float* __restrict__ W2, float* __restrict__ part)
{
    const int tid = threadIdx.x;
    const int lin = blockIdx.y * gridDim.x + blockIdx.x;
    const int vb  = (lin & 7) * 125 + (lin >> 3);
    const int n0 = (vb % 4) * 128;
    const int m0 = (vb / 4) * 128;
    const int lane = tid & 63, wid = tid >> 6;
    const int wm = (wid & 1) * 64, wn = (wid >> 1) * 64;

    __shared__ unsigned short As[3][128][32];
    __shared__ unsigned short Ws[3][128][32];

    f32x4 acc[4][4];
#pragma unroll
    for (int i = 0; i < 4; ++i)
#pragma unroll
        for (int j = 0; j < 4; ++j) acc[i][j] = (f32x4){0.f, 0.f, 0.f, 0.f};

    const unsigned short* gA0 = &A[(size_t)(m0 + wid * 16 + (lane >> 2)) * DDIM + (lane & 3) * 8];
    const unsigned short* gA1 = gA0 + (size_t)64 * DDIM;
    const unsigned short* gW0 = &W[(size_t)(n0 + wid * 16 + (lane >> 2)) * DDIM + (lane & 3) * 8];
    const unsigned short* gW1 = gW0 + (size_t)64 * DDIM;
    const int frow = lane & 15, fk = (lane >> 4) * 8;

    auto stage = [&](int buf, int k0) {
        gload16(gA0 + k0, &As[buf][wid * 16][0]);
        gload16(gA1 + k0, &As[buf][64 + wid * 16][0]);
        gload16(gW0 + k0, &Ws[buf][wid * 16][0]);
        gload16(gW1 + k0, &Ws[buf][64 + wid * 16][0]);
    };
    stage(0, 0);
    stage(1, 32);

    const int nst = DDIM / 32;   // 16
    for (int t = 0; t < nst; ++t) {
        const int cur = t % 3;
        if (t < nst - 1) asm volatile("s_waitcnt vmcnt(4)" ::: "memory");
        else             asm volatile("s_waitcnt vmcnt(0)" ::: "memory");
        __builtin_amdgcn_s_barrier();
        __builtin_amdgcn_sched_barrier(0);
        short8 af[4], wf[4];
#pragma unroll
        for (int mi = 0; mi < 4; ++mi)
            af[mi] = *(const short8*)&As[cur][wm + mi * 16 + frow][fk];
#pragma unroll
        for (int ni = 0; ni < 4; ++ni)
            wf[ni] = *(const short8*)&Ws[cur][wn + ni * 16 + frow][fk];
#pragma unroll
        for (int mi = 0; mi < 4; ++mi)
#pragma unroll
            for (int ni = 0; ni < 4; ++ni)
                acc[mi][ni] = __builtin_amdgcn_mfma_f32_16x16x32_bf16(
                    af[mi], wf[ni], acc[mi][ni], 0, 0, 0);
        if (t + 2 < nst) stage((t + 2) % 3, (t + 2) * 32);
    }

    if (MODE == 1) {
#pragma unroll
        for (int mi = 0; mi < 4; ++mi)
#pragma unroll
            for (int ni = 0; ni < 4; ++ni) {
                const int n = n0 + wn + ni * 16 + frow;
                const float bv = bias[n];
#pragma unroll
                for (int r = 0; r < 4; ++r) {
                    const int m = m0 + wm + mi * 16 + (lane >> 4) * 4 + r;
                    ((unsigned short*)outp)[(size_t)m * DDIM + n] =
                        f2bf(acc[mi][ni][r] + bv);
                }
            }
    } else {
        float w2v[4], bv4[4];
#pragma unroll
        for (int ni = 0; ni < 4; ++ni) {
            const int n = n0 + wn + ni * 16 + frow;
            w2v[ni] = W2[n];
            bv4[ni] = bias[n];
        }
        float ps[4][4];
#pragma unroll
        for (int mi = 0; mi < 4; ++mi)
#pragma unroll
            for (int r = 0; r < 4; ++r) ps[mi][r] = 0.f;
#pragma unroll
        for (int mi = 0; mi < 4; ++mi)
#pragma unroll
            for (int ni = 0; ni < 4; ++ni)
#pragma unroll
                for (int r = 0; r < 4; ++r)
                    ps[mi][r] += gelu_exact(acc[mi][ni][r] + bv4[ni]) * w2v[ni];
        const int slot = (n0 >> 7) * 2 + (wn >> 6);
#pragma unroll
        for (int mi = 0; mi < 4; ++mi)
#pragma unroll
            for (int r = 0; r < 4; ++r) {
                float s = ps[mi][r];
                s += __shfl_xor(s, 1, 64);
                s += __shfl_xor(s, 2, 64);
                s += __shfl_xor(s, 4, 64);
                s += __shfl_xor(s, 8, 64);
                if (frow == 0) {
                    const int m = m0 + wm + mi * 16 + (lane >> 4) * 4 + r;
                    part[(size_t)m * 8 + slot] = s;
                }
            }
    }
}

// ---------------------------------------------------------------------------
// Final reduction: out[m] = b2 + sum of 8 partials.
// ---------------------------------------------------------------------------
__global__ __launch_bounds__(256) void w2red_kernel(
    const float* __restrict__ part, const float* __restrict__ b2,
    float* __restrict__ out)
{
    const int m = blockIdx.x * 256 + threadIdx.x;
    if (m >= MTOT) return;
    const float* p = part + (size_t)m * 8;
    float s = b2[0];
#pragma unroll
    for (int i = 0; i < 8; ++i) s += p[i];
    out[m] = s;
}

// ---------------------------------------------------------------------------
// Attention (unchanged): compacted keys, bf16 score LDS, barrier-free loops.
// ---------------------------------------------------------------------------
__global__ __launch_bounds__(256) void attn_mfma(
    const unsigned short* __restrict__ qx, const unsigned short* __restrict__ kc,
    const unsigned short* __restrict__ vc, const int* __restrict__ cnt,
    unsigned short* __restrict__ outb)
{
    const int s0 = blockIdx.x, h = blockIdx.y, b = blockIdx.z;
    const int tid = threadIdx.x, lane = tid & 63, w = tid >> 6;
    const int nck = cnt[b * 32 + s0];
    const int NT = (nck + 63) >> 6;
    const int NK = NT << 6;

    __shared__ __align__(16) unsigned short scb[KPS][520];
    __shared__ float invb[KPS];

    const int frow = lane & 15, fk = (lane >> 4) * 8;
    const size_t bh = (size_t)b * HEADS + h;
    const unsigned short* kbase = kc + bh * (CMAX * HD);
    const unsigned short* vbase = vc + bh * (HD * CMAX);

    short8 qf[2][2];
#pragma unroll
    for (int mi = 0; mi < 2; ++mi) {
        const int qrow = mi * 16 + frow;
#pragma unroll
        for (int ks = 0; ks < 2; ++ks) {
            short8 v = {};
            if (qrow < KPS)
                v = *(const short8*)&qx[(bh * LFULL + s0 * KPS + 1 + qrow) * HD
                                        + ks * 32 + fk];
            qf[mi][ks] = v;
        }
    }

    for (int t = 0; t < NT; ++t) {
        const int key = (t << 6) + w * 16 + frow;
        const unsigned short* kr = kbase + (size_t)key * HD;
        const short8 kf0 = *(const short8*)(kr + fk);
        const short8 kf1 = *(const short8*)(kr + 32 + fk);
        f32x4 s2[2];
#pragma unroll
        for (int mi = 0; mi < 2; ++mi) {
            s2[mi] = (f32x4){0.f, 0.f, 0.f, 0.f};
            s2[mi] = __builtin_amdgcn_mfma_f32_16x16x32_bf16(qf[mi][0], kf0, s2[mi], 0, 0, 0);
            s2[mi] = __builtin_amdgcn_mfma_f32_16x16x32_bf16(qf[mi][1], kf1, s2[mi], 0, 0, 0);
        }
        const bool allow = key < nck;
#pragma unroll
        for (int mi = 0; mi < 2; ++mi)
#pragma unroll
            for (int r = 0; r < 4; ++r) {
                const int row = mi * 16 + (lane >> 4) * 4 + r;
                if (row < KPS)
                    scb[row][key] = f2bf(allow ? s2[mi][r] * 0.125f : -1e30f);
            }
    }
    __syncthreads();

    for (int r = w; r < KPS; r += 4) {
        float xv[8];
        float mx = -1e30f;
#pragma unroll
        for (int i = 0; i < 8; ++i) {
            const int k_ = lane + i * 64;
            if (k_ < NK) { xv[i] = bf2f(scb[r][k_]); mx = fmaxf(mx, xv[i]); }
        }
#pragma unroll
        for (int off = 32; off; off >>= 1) mx = fmaxf(mx, __shfl_xor(mx, off, 64));
        float ss = 0.f;
#pragma unroll
        for (int i = 0; i < 8; ++i) {
            const int k_ = lane + i * 64;
            if (k_ < NK) {
                const float p = __expf(xv[i] - mx);
                ss += p;
                scb[r][k_] = f2bf(p);
            }
        }
#pragma unroll
        for (int off = 32; off; off >>= 1) ss += __shfl_xor(ss, off, 64);
        if (lane == 0) invb[r] = 1.0f / ss;
    }
    __syncthreads();

    f32x4 po[2];
    po[0] = (f32x4){0.f, 0.f, 0.f, 0.f};
    po[1] = (f32x4){0.f, 0.f, 0.f, 0.f};
    const unsigned short* vrow = vbase + (size_t)(w * 16 + frow) * CMAX;
    for (int t = 0; t < NT; ++t) {
#pragma unroll
        for (int ks = 0; ks < 2; ++ks) {
            const int kb0 = (t << 6) + ks * 32 + fk;
            short8 vf;
            if (t + 1 < NT) {
                vf = *(const short8*)(vrow + kb0);
            } else if (kb0 + 8 <= nck) {
                vf = *(const short8*)(vrow + kb0);
            } else {
#pragma unroll
                for (int j = 0; j < 8; ++j)
                    vf[j] = (kb0 + j < nck) ? (short)vrow[kb0 + j] : (short)0;
            }
#pragma unroll
            for (int mi = 0; mi < 2; ++mi) {
                short8 pf = {};
                const int prow = mi * 16 + frow;
                if (prow < KPS)
                    pf = *(const short8*)&scb[prow][kb0];
                po[mi] = __builtin_amdgcn_mfma_f32_16x16x32_bf16(pf, vf, po[mi], 0, 0, 0);
            }
        }
    }

#pragma unroll
    for (int mi = 0; mi < 2; ++mi)
#pragma unroll
        for (int r = 0; r < 4; ++r) {
            const int row = mi * 16 + (lane >> 4) * 4 + r;
            if (row < KPS)
                outb[((size_t)b * NROWS + s0 * KPS + row) * DDIM
                     + h * HD + w * 16 + frow] = f2bf(po[mi][r] * invb[row]);
        }
}

// ---------------------------------------------------------------------------
// LayerNorm bf16 -> bf16. One wave per row, 16B/lane loads.
// ---------------------------------------------------------------------------
__global__ __launch_bounds__(256) void ln_kernel(
    const unsigned short* __restrict__ f, const float* __restrict__ g,
    const float* __restrict__ bt, unsigned short* __restrict__ o)
{
    const int row = blockIdx.x * 4 + (threadIdx.x >> 6);
    const int lane = threadIdx.x & 63;
    const size_t base = (size_t)row * DDIM + lane * 8;
    short8 v = *(const short8*)&f[base];
    float xv[8];
    float s = 0.f;
#pragma unroll
    for (int i = 0; i < 8; ++i) { xv[i] = bf2f((unsigned short)v[i]); s += xv[i]; }
#pragma unroll
    for (int off = 32; off; off >>= 1) s += __shfl_xor(s, off, 64);
    const float mu = s * (1.0f / DDIM);
    float var = 0.f;
#pragma unroll
    for (int i = 0; i < 8; ++i) { const float d0 = xv[i] - mu; var += d0 * d0; }
#pragma unroll
    for (int off = 32; off; off >>= 1) var += __shfl_xor(var, off, 64);
    const float rs = rsqrtf(var * (1.0f / DDIM) + 1e-5f);
    short8 ov;
#pragma unroll
    for (int i = 0; i < 8; ++i) {
        const int d0 = lane * 8 + i;
        ov[i] = (short)f2bf((xv[i] - mu) * rs * g[d0] + bt[d0]);
    }
    *(short8*)&o[base] = ov;
}

// ---------------------------------------------------------------------------
extern "C" void kernel_launch(void* const* d_in, const int* in_sizes, int n_in,
                              void* d_out, int out_size, void* d_ws, size_t ws_size,
                              hipStream_t stream)
{
    const float* item = (const float*)d_in[0];
    const float* user = (const float*)d_in[1];
    const int*   resp = (const int*)d_in[2];
    const float* Wq = (const float*)d_in[3];  const float* bq = (const float*)d_in[4];
    const float* Wk = (const float*)d_in[5];  const float* bk = (const float*)d_in[6];
    const float* Wv = (const float*)d_in[7];  const float* bv = (const float*)d_in[8];
    const float* Wo = (const float*)d_in[9];  const float* bo = (const float*)d_in[10];
    const float* lng = (const float*)d_in[11]; const float* lnb = (const float*)d_in[12];
    const float* W1 = (const float*)d_in[13]; const float* b1 = (const float*)d_in[14];
    const float* W2 = (const float*)d_in[15]; const float* b2 = (const float*)d_in[16];
    float* out = (float*)d_out;

    char* p = (char*)d_ws;
    auto alloc = [&](size_t bytes) { char* r = p; p += (bytes + 255) & ~(size_t)255; return r; };
    const size_t NITEM = (size_t)BATCH * NROWS * EDIM;
    const size_t NW    = (size_t)DDIM * DDIM;
    const size_t NQ    = (size_t)BATCH * HEADS * LFULL * HD;
    const size_t NC    = (size_t)BATCH * HEADS * CMAX * HD;
    const size_t NMD   = (size_t)MTOT * DDIM;
    const size_t PAD   = 8192;

    unsigned short* itemb  = (unsigned short*)alloc(NITEM * 2);
    unsigned short* Wqkvb  = (unsigned short*)alloc((size_t)NQKV * EDIM * 2);
    unsigned short* Wob    = (unsigned short*)alloc(NW * 2);
    unsigned short* W1b    = (unsigned short*)alloc(NW * 2);
    unsigned short* qb     = (unsigned short*)alloc(NQ * 2 + PAD);
    unsigned short* kcb    = (unsigned short*)alloc(NC * 2 + PAD);
    unsigned short* vcb    = (unsigned short*)alloc(NC * 2 + PAD);
    unsigned short* aob    = (unsigned short*)alloc(NMD * 2);
    unsigned short* fb16   = (unsigned short*)alloc(NMD * 2);
    float* uball = (float*)alloc((size_t)BATCH * NQKV * 4);
    float* part  = (float*)alloc((size_t)MTOT * 8 * 4);
    int* cidx    = (int*)alloc((size_t)BATCH * 512 * 4);
    int* cnt     = (int*)alloc((size_t)BATCH * 32 * 4);

    cvt_kernel<<<dim3((NITEM / 4 + 255) / 256), 256, 0, stream>>>(item, itemb, NITEM / 4);
    packqkv_kernel<<<dim3(DDIM * EDIM / 4 / 256, 3), 256, 0, stream>>>(Wq, Wk, Wv, Wqkvb);
    Cvt2 c2;
    c2.s[0] = Wo; c2.s[1] = W1; c2.d[0] = Wob; c2.d[1] = W1b;
    cvt2_kernel<<<dim3(NW / 4 / 256, 2), 256, 0, stream>>>(c2, NW / 4);

    compact_kernel<<<dim3(BATCH), 64, 0, stream>>>(resp, cidx, cnt);

    user_bias_kernel<<<dim3(BATCH, 3), 256, 0, stream>>>(
        user, Wq, bq, Wk, bk, Wv, bv, uball, qb, kcb, vcb);

    gemm_qkv<<<dim3(NQKV / 128, MTOT / 128), 256, 0, stream>>>(
        itemb, Wqkvb, uball, cidx, qb, kcb, vcb);

    attn_mfma<<<dim3(SLATES, HEADS, BATCH), 256, 0, stream>>>(qb, kcb, vcb, cnt, aob);

    dim3 gg(DDIM / 128, MTOT / 128);
    // f = ao @ Wo^T + bo  (bf16 out)
    gemm_bf16<1><<<gg, 256, 0, stream>>>(aob, Wob, bo, fb16, nullptr, nullptr);
    ln_kernel<<<dim3(MTOT / 4), 256, 0, stream>>>(fb16, lng, lnb, aob);
    // h = gelu(ln @ W1^T + b1) . W2 partials
    gemm_bf16<2><<<gg, 256, 0, stream>>>(aob, W1b, b1, nullptr, W2, part);
    w2red_kernel<<<dim3((MTOT + 255) / 256), 256, 0, stream>>>(part, b2, out);
}

// Round 10
// 295.368 us; speedup vs baseline: 1.4517x; 1.0346x over previous
//
#include <hip/hip_runtime.h>
#include <math.h>

#define BATCH 64
#define SLATES 25
#define KPS 20
#define EDIM 256
#define DDIM 512
#define HEADS 8
#define HD 64
#define LFULL 501
#define NROWS 500
#define MTOT (BATCH*NROWS)   // 32000
#define CMAX 512             // compacted key capacity
#define NQKV 1536            // packed q|k|v output dim

typedef __attribute__((ext_vector_type(8))) short short8;
typedef __attribute__((ext_vector_type(4))) float f32x4;

__device__ __forceinline__ unsigned short f2bf(float x) {
    unsigned int u = __builtin_bit_cast(unsigned int, x);
    u = (u + 0x7FFFu + ((u >> 16) & 1u)) >> 16;
    return (unsigned short)u;
}
__device__ __forceinline__ float bf2f(unsigned short s) {
    unsigned int u = ((unsigned int)s) << 16;
    return __builtin_bit_cast(float, u);
}
__device__ __forceinline__ float gelu_exact(float x) {
    return 0.5f * x * (1.0f + erff(x * 0.70710678118654752440f));
}
__device__ __forceinline__ void gload16(const void* g, void* l) {
    __builtin_amdgcn_global_load_lds(
        (const __attribute__((address_space(1))) void*)g,
        (__attribute__((address_space(3))) void*)l, 16, 0, 0);
}

// ---------------------------------------------------------------------------
// fp32 -> bf16 converts / weight packing
// ---------------------------------------------------------------------------
__global__ __launch_bounds__(256) void cvt_kernel(
    const float* __restrict__ src, unsigned short* __restrict__ dst, int n4)
{
    const int i = blockIdx.x * 256 + threadIdx.x;
    if (i >= n4) return;
    float4 v = ((const float4*)src)[i];
    ushort4 o;
    o.x = f2bf(v.x); o.y = f2bf(v.y); o.z = f2bf(v.z); o.w = f2bf(v.w);
    ((ushort4*)dst)[i] = o;
}

struct Cvt2 { const float* s[2]; unsigned short* d[2]; };
__global__ __launch_bounds__(256) void cvt2_kernel(Cvt2 a, int n4)
{
    const int i = blockIdx.x * 256 + threadIdx.x;
    if (i >= n4) return;
    const int y = blockIdx.y;
    float4 v = ((const float4*)a.s[y])[i];
    ushort4 o;
    o.x = f2bf(v.x); o.y = f2bf(v.y); o.z = f2bf(v.z); o.w = f2bf(v.w);
    ((ushort4*)a.d[y])[i] = o;
}

// Pack [Wq;Wk;Wv][:, 0:256] -> (1536 x 256) bf16
__global__ __launch_bounds__(256) void packqkv_kernel(
    const float* __restrict__ Wq, const float* __restrict__ Wk,
    const float* __restrict__ Wv, unsigned short* __restrict__ dst)
{
    const int y = blockIdx.y;
    const float* W = (y == 0) ? Wq : (y == 1) ? Wk : Wv;
    const int i = blockIdx.x * 256 + threadIdx.x;
    const int row = i >> 6, c4 = (i & 63) * 4;
    float4 v = *(const float4*)&W[(size_t)row * DDIM + c4];
    ushort4 o;
    o.x = f2bf(v.x); o.y = f2bf(v.y); o.z = f2bf(v.z); o.w = f2bf(v.w);
    *(ushort4*)&dst[((size_t)y * DDIM + row) * EDIM + c4] = o;
}

// ---------------------------------------------------------------------------
// Click compaction: one wave per batch.
// ---------------------------------------------------------------------------
__global__ __launch_bounds__(64) void compact_kernel(
    const int* __restrict__ resp, int* __restrict__ cidx, int* __restrict__ cnt)
{
    const int b = blockIdx.x, lane = threadIdx.x;
    int a[8]; int c = 0;
#pragma unroll
    for (int j = 0; j < 8; ++j) {
        const int l = lane * 8 + j;
        int al = 0;
        if (l == 0) al = 1;
        else if (l <= NROWS) al = (resp[(size_t)b * NROWS + l - 1] > 0) ? 1 : 0;
        a[j] = al; c += al;
    }
    int incl = c;
#pragma unroll
    for (int off = 1; off < 64; off <<= 1) {
        int t = __shfl_up(incl, off, 64);
        if (lane >= off) incl += t;
    }
    int run = incl - c;
#pragma unroll
    for (int j = 0; j < 8; ++j) {
        const int l = lane * 8 + j;
        if (l >= 1 && l <= 481 && (l % 20) == 1)
            cnt[b * 32 + (l - 1) / 20] = run;
        cidx[b * 512 + l] = a[j] ? run : -1;
        run += a[j];
    }
}

// ---------------------------------------------------------------------------
// Per-batch user bias tables (packed [B][1536]) + position-0 rows.
// ---------------------------------------------------------------------------
__global__ __launch_bounds__(256) void user_bias_kernel(
    const float* __restrict__ user,
    const float* __restrict__ Wq, const float* __restrict__ bq,
    const float* __restrict__ Wk, const float* __restrict__ bk,
    const float* __restrict__ Wv, const float* __restrict__ bv,
    float* __restrict__ uball,
    unsigned short* __restrict__ qb, unsigned short* __restrict__ kc,
    unsigned short* __restrict__ vc)
{
    const int b = blockIdx.x;
    const int y = blockIdx.y;
    const int tid = threadIdx.x;
    const float* W  = (y == 0) ? Wq : (y == 1) ? Wk : Wv;
    const float* bi = (y == 0) ? bq : (y == 1) ? bk : bv;

    __shared__ float us[EDIM];
    if (tid < EDIM) us[tid] = user[b * EDIM + tid];
    __syncthreads();
    for (int o = tid; o < DDIM; o += 256) {
        float s = bi[o];
        const float* wr = &W[(size_t)o * DDIM + EDIM];
#pragma unroll 4
        for (int e = 0; e < EDIM; ++e) s += us[e] * wr[e];
        uball[(size_t)b * NQKV + y * DDIM + o] = s;
        const int hh = o >> 6, dd = o & 63;
        const size_t bh = (size_t)b * HEADS + hh;
        if (y == 0)      qb[(bh * LFULL) * HD + dd] = f2bf(bi[o]);
        else if (y == 1) kc[(bh * CMAX) * HD + dd] = f2bf(bi[o]);
        else             vc[(bh * HD + dd) * CMAX] = f2bf(bi[o]);
    }
}

// ---------------------------------------------------------------------------
// Merged QKV GEMM: counted-vmcnt 3-buffer pipeline + LDS-bounce coalesced
// epilogue + XCD-chunked block swizzle. Grid = (12, 250) = 3000 blocks.
// ---------------------------------------------------------------------------
__global__ __launch_bounds__(256) void gemm_qkv(
    const unsigned short* __restrict__ A,
    const unsigned short* __restrict__ Wqkv,
    const float* __restrict__ uball, const int* __restrict__ cidx,
    unsigned short* __restrict__ oq, unsigned short* __restrict__ ok,
    unsigned short* __restrict__ ov)
{
    const int tid = threadIdx.x;
    // XCD-chunked bijective swizzle: 3000 blocks = 8 XCDs x 375
    const int lin = blockIdx.y * gridDim.x + blockIdx.x;
    const int vb  = (lin & 7) * 375 + (lin >> 3);
    const int n0 = (vb % 12) * 128;   // 0..1535
    const int m0 = (vb / 12) * 128;
    const int lane = tid & 63, wid = tid >> 6;
    const int wm = (wid & 1) * 64, wn = (wid >> 1) * 64;

    __shared__ __align__(16) unsigned short sm[24576];
    __shared__ int cids[128];
    auto As = [&](int buf) { return (unsigned short(*)[32])(sm + buf * 4096); };
    auto Ws = [&](int buf) { return (unsigned short(*)[32])(sm + 12288 + buf * 4096); };
    auto bounce = (unsigned short(*)[136])sm;

    f32x4 acc[4][4];
#pragma unroll
    for (int i = 0; i < 4; ++i)
#pragma unroll
        for (int j = 0; j < 4; ++j) acc[i][j] = (f32x4){0.f, 0.f, 0.f, 0.f};

    const unsigned short* gA0 = &A[(size_t)(m0 + wid * 16 + (lane >> 2)) * EDIM + (lane & 3) * 8];
    const unsigned short* gA1 = gA0 + (size_t)64 * EDIM;
    const unsigned short* gW0 = &Wqkv[(size_t)(n0 + wid * 16 + (lane >> 2)) * EDIM + (lane & 3) * 8];
    const unsigned short* gW1 = gW0 + (size_t)64 * EDIM;
    const int frow = lane & 15, fk = (lane >> 4) * 8;

    auto stage = [&](int buf, int k0) {
        gload16(gA0 + k0, &As(buf)[wid * 16][0]);
        gload16(gA1 + k0, &As(buf)[64 + wid * 16][0]);
        gload16(gW0 + k0, &Ws(buf)[wid * 16][0]);
        gload16(gW1 + k0, &Ws(buf)[64 + wid * 16][0]);
    };
    stage(0, 0);
    stage(1, 32);

    const int nst = EDIM / 32;   // 8
    for (int t = 0; t < nst; ++t) {
        const int cur = t % 3;
        if (t < nst - 1) asm volatile("s_waitcnt vmcnt(4)" ::: "memory");
        else             asm volatile("s_waitcnt vmcnt(0)" ::: "memory");
        __builtin_amdgcn_s_barrier();
        __builtin_amdgcn_sched_barrier(0);
        short8 af[4], wf[4];
#pragma unroll
        for (int mi = 0; mi < 4; ++mi)
            af[mi] = *(const short8*)&As(cur)[wm + mi * 16 + frow][fk];
#pragma unroll
        for (int ni = 0; ni < 4; ++ni)
            wf[ni] = *(const short8*)&Ws(cur)[wn + ni * 16 + frow][fk];
#pragma unroll
        for (int mi = 0; mi < 4; ++mi)
#pragma unroll
            for (int ni = 0; ni < 4; ++ni)
                acc[mi][ni] = __builtin_amdgcn_mfma_f32_16x16x32_bf16(
                    af[mi], wf[ni], acc[mi][ni], 0, 0, 0);
        if (t + 2 < nst) stage((t + 2) % 3, (t + 2) * 32);
    }

    // ---- epilogue: bounce through LDS for coalesced stores ----
    const int z = n0 >> 9;               // 0=q 1=k 2=v
    const int b0 = m0 / NROWS;
    const int split = (b0 + 1) * NROWS;
    const int b1 = (split <= m0 + 127) ? b0 + 1 : b0;
    float ub0[4], ub1[4];
#pragma unroll
    for (int ni = 0; ni < 4; ++ni) {
        const int np = n0 + wn + ni * 16 + frow;
        ub0[ni] = uball[(size_t)b0 * NQKV + np];
        ub1[ni] = uball[(size_t)b1 * NQKV + np];
    }
    __syncthreads();
    if (z != 0 && tid < 128) {
        const int m = m0 + tid;
        const int b = (m >= split) ? b1 : b0;
        cids[tid] = cidx[b * 512 + (m - b * NROWS + 1)];
    }
#pragma unroll
    for (int mi = 0; mi < 4; ++mi)
#pragma unroll
        for (int r = 0; r < 4; ++r) {
            const int ml = wm + mi * 16 + (lane >> 4) * 4 + r;
            const bool hi = (m0 + ml >= split);
#pragma unroll
            for (int ni = 0; ni < 4; ++ni)
                bounce[ml][wn + ni * 16 + frow] =
                    f2bf(acc[mi][ni][r] + (hi ? ub1[ni] : ub0[ni]));
        }
    __syncthreads();

    const int h0 = (n0 & 511) >> 6;
    if (z == 0) {
        const int row = tid >> 1, half = tid & 1;
        const int m = m0 + row;
        const int b = (m >= split) ? b1 : b0;
        const int l = m - b * NROWS + 1;
        unsigned short* dst = &oq[(((size_t)b * HEADS + h0 + half) * LFULL + l) * HD];
        const unsigned short* src = &bounce[row][half * 64];
#pragma unroll
        for (int j = 0; j < 8; ++j)
            *(uint4*)(dst + j * 8) = *(const uint4*)(src + j * 8);
    } else if (z == 1) {
        const int row = tid >> 1, half = tid & 1;
        const int c = cids[row];
        if (c >= 0) {
            const int m = m0 + row;
            const int b = (m >= split) ? b1 : b0;
            unsigned short* dst = &ok[(((size_t)b * HEADS + h0 + half) * CMAX + c) * HD];
            const unsigned short* src = &bounce[row][half * 64];
#pragma unroll
            for (int j = 0; j < 8; ++j)
                *(uint4*)(dst + j * 8) = *(const uint4*)(src + j * 8);
        }
    } else {
        const int col = tid & 127, mh = tid >> 7;
        const int hh = h0 + (col >> 6), dd = col & 63;
        for (int mm = 0; mm < 64; ++mm) {
            const int row = mh * 64 + mm;
            const int c = cids[row];
            if (c >= 0) {
                const int m = m0 + row;
                const int b = (m >= split) ? b1 : b0;
                ov[((size_t)b * HEADS + hh) * (size_t)(HD * CMAX)
                   + (size_t)dd * CMAX + c] = bounce[row][col];
            }
        }
    }
}

// ---------------------------------------------------------------------------
// Generic bf16 GEMM (counted-vmcnt 3-buffer) + XCD swizzle (1000 = 8 x 125).
// MODE 1: +bias, bf16 out. MODE 2: +bias, gelu, dot W2 -> 8 partials/row.
// ---------------------------------------------------------------------------
template <int MODE>
__global__ __launch_bounds__(256) void gemm_bf16(
    const unsigned short* __restrict__ A,
    const unsigned short* __restrict__ W,
    const float* __restrict__ bias, void* __restrict__ outp,
    const float* __restrict__ W2, float* __restrict__ part)
{
    const int tid = threadIdx.x;
    const int lin = blockIdx.y * gridDim.x + blockIdx.x;
    const int vb  = (lin & 7) * 125 + (lin >> 3);
    const int n0 = (vb % 4) * 128;
    const int m0 = (vb / 4) * 128;
    const int lane = tid & 63, wid = tid >> 6;
    const int wm = (wid & 1) * 64, wn = (wid >> 1) * 64;

    __shared__ unsigned short As[3][128][32];
    __shared__ unsigned short Ws[3][128][32];

    f32x4 acc[4][4];
#pragma unroll
    for (int i = 0; i < 4; ++i)
#pragma unroll
        for (int j = 0; j < 4; ++j) acc[i][j] = (f32x4){0.f, 0.f, 0.f, 0.f};

    const unsigned short* gA0 = &A[(size_t)(m0 + wid * 16 + (lane >> 2)) * DDIM + (lane & 3) * 8];
    const unsigned short* gA1 = gA0 + (size_t)64 * DDIM;
    const unsigned short* gW0 = &W[(size_t)(n0 + wid * 16 + (lane >> 2)) * DDIM + (lane & 3) * 8];
    const unsigned short* gW1 = gW0 + (size_t)64 * DDIM;
    const int frow = lane & 15, fk = (lane >> 4) * 8;

    auto stage = [&](int buf, int k0) {
        gload16(gA0 + k0, &As[buf][wid * 16][0]);
        gload16(gA1 + k0, &As[buf][64 + wid * 16][0]);
        gload16(gW0 + k0, &Ws[buf][wid * 16][0]);
        gload16(gW1 + k0, &Ws[buf][64 + wid * 16][0]);
    };
    stage(0, 0);
    stage(1, 32);

    const int nst = DDIM / 32;   // 16
    for (int t = 0; t < nst; ++t) {
        const int cur = t % 3;
        if (t < nst - 1) asm volatile("s_waitcnt vmcnt(4)" ::: "memory");
        else             asm volatile("s_waitcnt vmcnt(0)" ::: "memory");
        __builtin_amdgcn_s_barrier();
        __builtin_amdgcn_sched_barrier(0);
        short8 af[4], wf[4];
#pragma unroll
        for (int mi = 0; mi < 4; ++mi)
            af[mi] = *(const short8*)&As[cur][wm + mi * 16 + frow][fk];
#pragma unroll
        for (int ni = 0; ni < 4; ++ni)
            wf[ni] = *(const short8*)&Ws[cur][wn + ni * 16 + frow][fk];
#pragma unroll
        for (int mi = 0; mi < 4; ++mi)
#pragma unroll
            for (int ni = 0; ni < 4; ++ni)
                acc[mi][ni] = __builtin_amdgcn_mfma_f32_16x16x32_bf16(
                    af[mi], wf[ni], acc[mi][ni], 0, 0, 0);
        if (t + 2 < nst) stage((t + 2) % 3, (t + 2) * 32);
    }

    if (MODE == 1) {
#pragma unroll
        for (int mi = 0; mi < 4; ++mi)
#pragma unroll
            for (int ni = 0; ni < 4; ++ni) {
                const int n = n0 + wn + ni * 16 + frow;
                const float bv = bias[n];
#pragma unroll
                for (int r = 0; r < 4; ++r) {
                    const int m = m0 + wm + mi * 16 + (lane >> 4) * 4 + r;
                    ((unsigned short*)outp)[(size_t)m * DDIM + n] =
                        f2bf(acc[mi][ni][r] + bv);
                }
            }
    } else {
        float w2v[4], bv4[4];
#pragma unroll
        for (int ni = 0; ni < 4; ++ni) {
            const int n = n0 + wn + ni * 16 + frow;
            w2v[ni] = W2[n];
            bv4[ni] = bias[n];
        }
        float ps[4][4];
#pragma unroll
        for (int mi = 0; mi < 4; ++mi)
#pragma unroll
            for (int r = 0; r < 4; ++r) ps[mi][r] = 0.f;
#pragma unroll
        for (int mi = 0; mi < 4; ++mi)
#pragma unroll
            for (int ni = 0; ni < 4; ++ni)
#pragma unroll
                for (int r = 0; r < 4; ++r)
                    ps[mi][r] += gelu_exact(acc[mi][ni][r] + bv4[ni]) * w2v[ni];
        const int slot = (n0 >> 7) * 2 + (wn >> 6);
#pragma unroll
        for (int mi = 0; mi < 4; ++mi)
#pragma unroll
            for (int r = 0; r < 4; ++r) {
                float s = ps[mi][r];
                s += __shfl_xor(s, 1, 64);
                s += __shfl_xor(s, 2, 64);
                s += __shfl_xor(s, 4, 64);
                s += __shfl_xor(s, 8, 64);
                if (frow == 0) {
                    const int m = m0 + wm + mi * 16 + (lane >> 4) * 4 + r;
                    part[(size_t)m * 8 + slot] = s;
                }
            }
    }
}

// ---------------------------------------------------------------------------
// Final reduction: out[m] = b2 + sum of 8 partials.
// ---------------------------------------------------------------------------
__global__ __launch_bounds__(256) void w2red_kernel(
    const float* __restrict__ part, const float* __restrict__ b2,
    float* __restrict__ out)
{
    const int m = blockIdx.x * 256 + threadIdx.x;
    if (m >= MTOT) return;
    const float* p = part + (size_t)m * 8;
    float s = b2[0];
#pragma unroll
    for (int i = 0; i < 8; ++i) s += p[i];
    out[m] = s;
}

// ---------------------------------------------------------------------------
// Attention v6: fused exp in QK^T epilogue (no max pass, no softmax phase),
// register row-sum partials, XCD-chunked swizzle (12800 = 8 x 1600).
// ---------------------------------------------------------------------------
__global__ __launch_bounds__(256) void attn_mfma(
    const unsigned short* __restrict__ qx, const unsigned short* __restrict__ kc,
    const unsigned short* __restrict__ vc, const int* __restrict__ cnt,
    unsigned short* __restrict__ outb)
{
    // swizzle: all 25 slates of 64 consecutive (b,h) groups land on one XCD
    const int lin = blockIdx.x + SLATES * (blockIdx.y + HEADS * blockIdx.z);
    const int vbk = (lin & 7) * 1600 + (lin >> 3);
    const int s0 = vbk % SLATES;
    const int h  = (vbk / SLATES) % HEADS;
    const int b  = vbk / (SLATES * HEADS);

    const int tid = threadIdx.x, lane = tid & 63, w = tid >> 6;
    const int nck = cnt[b * 32 + s0];
    const int NT = (nck + 63) >> 6;

    __shared__ __align__(16) unsigned short scb[KPS][520];  // bf16 P
    __shared__ float rsw[4][32];                            // per-wave row sums

    const int frow = lane & 15, fk = (lane >> 4) * 8;
    const size_t bh = (size_t)b * HEADS + h;
    const unsigned short* kbase = kc + bh * (CMAX * HD);
    const unsigned short* vbase = vc + bh * (HD * CMAX);

    short8 qf[2][2];
#pragma unroll
    for (int mi = 0; mi < 2; ++mi) {
        const int qrow = mi * 16 + frow;
#pragma unroll
        for (int ks = 0; ks < 2; ++ks) {
            short8 v = {};
            if (qrow < KPS)
                v = *(const short8*)&qx[(bh * LFULL + s0 * KPS + 1 + qrow) * HD
                                        + ks * 32 + fk];
            qf[mi][ks] = v;
        }
    }

    // ---- QK^T + fused exp + row-sum partials (barrier-free) ----
    f32x4 rsum[2];
    rsum[0] = (f32x4){0.f, 0.f, 0.f, 0.f};
    rsum[1] = (f32x4){0.f, 0.f, 0.f, 0.f};
    for (int t = 0; t < NT; ++t) {
        const int key = (t << 6) + w * 16 + frow;
        const unsigned short* kr = kbase + (size_t)key * HD;
        const short8 kf0 = *(const short8*)(kr + fk);
        const short8 kf1 = *(const short8*)(kr + 32 + fk);
        f32x4 s2[2];
#pragma unroll
        for (int mi = 0; mi < 2; ++mi) {
            s2[mi] = (f32x4){0.f, 0.f, 0.f, 0.f};
            s2[mi] = __builtin_amdgcn_mfma_f32_16x16x32_bf16(qf[mi][0], kf0, s2[mi], 0, 0, 0);
            s2[mi] = __builtin_amdgcn_mfma_f32_16x16x32_bf16(qf[mi][1], kf1, s2[mi], 0, 0, 0);
        }
        const bool allow = key < nck;
#pragma unroll
        for (int mi = 0; mi < 2; ++mi)
#pragma unroll
            for (int r = 0; r < 4; ++r) {
                const int row = mi * 16 + (lane >> 4) * 4 + r;
                const float p = allow ? __expf(s2[mi][r] * 0.125f) : 0.f;
                rsum[mi][r] += p;
                if (row < KPS)
                    scb[row][key] = f2bf(p);
            }
    }
    // reduce partials over the 16 frow lanes (bits 0..3 of lane)
#pragma unroll
    for (int mi = 0; mi < 2; ++mi)
#pragma unroll
        for (int r = 0; r < 4; ++r) {
            float v = rsum[mi][r];
            v += __shfl_xor(v, 1, 64);
            v += __shfl_xor(v, 2, 64);
            v += __shfl_xor(v, 4, 64);
            v += __shfl_xor(v, 8, 64);
            if (frow == 0)
                rsw[w][mi * 16 + (lane >> 4) * 4 + r] = v;
        }
    __syncthreads();

    // ---- PV (barrier-free; wave w owns dims w*16..w*16+15) ----
    f32x4 po[2];
    po[0] = (f32x4){0.f, 0.f, 0.f, 0.f};
    po[1] = (f32x4){0.f, 0.f, 0.f, 0.f};
    const unsigned short* vrow = vbase + (size_t)(w * 16 + frow) * CMAX;
    for (int t = 0; t < NT; ++t) {
#pragma unroll
        for (int ks = 0; ks < 2; ++ks) {
            const int kb0 = (t << 6) + ks * 32 + fk;
            short8 vf;
            if (t + 1 < NT || kb0 + 8 <= nck) {
                vf = *(const short8*)(vrow + kb0);
            } else {
#pragma unroll
                for (int j = 0; j < 8; ++j)
                    vf[j] = (kb0 + j < nck) ? (short)vrow[kb0 + j] : (short)0;
            }
#pragma unroll
            for (int mi = 0; mi < 2; ++mi) {
                short8 pf = {};
                const int prow = mi * 16 + frow;
                if (prow < KPS)
                    pf = *(const short8*)&scb[prow][kb0];
                po[mi] = __builtin_amdgcn_mfma_f32_16x16x32_bf16(pf, vf, po[mi], 0, 0, 0);
            }
        }
    }

#pragma unroll
    for (int mi = 0; mi < 2; ++mi)
#pragma unroll
        for (int r = 0; r < 4; ++r) {
            const int row = mi * 16 + (lane >> 4) * 4 + r;
            if (row < KPS) {
                const float inv = 1.0f / (rsw[0][row] + rsw[1][row]
                                        + rsw[2][row] + rsw[3][row]);
                outb[((size_t)b * NROWS + s0 * KPS + row) * DDIM
                     + h * HD + w * 16 + frow] = f2bf(po[mi][r] * inv);
            }
        }
}

// ---------------------------------------------------------------------------
// LayerNorm bf16 -> bf16. One wave per row, 16B/lane loads.
// ---------------------------------------------------------------------------
__global__ __launch_bounds__(256) void ln_kernel(
    const unsigned short* __restrict__ f, const float* __restrict__ g,
    const float* __restrict__ bt, unsigned short* __restrict__ o)
{
    const int row = blockIdx.x * 4 + (threadIdx.x >> 6);
    const int lane = threadIdx.x & 63;
    const size_t base = (size_t)row * DDIM + lane * 8;
    short8 v = *(const short8*)&f[base];
    float xv[8];
    float s = 0.f;
#pragma unroll
    for (int i = 0; i < 8; ++i) { xv[i] = bf2f((unsigned short)v[i]); s += xv[i]; }
#pragma unroll
    for (int off = 32; off; off >>= 1) s += __shfl_xor(s, off, 64);
    const float mu = s * (1.0f / DDIM);
    float var = 0.f;
#pragma unroll
    for (int i = 0; i < 8; ++i) { const float d0 = xv[i] - mu; var += d0 * d0; }
#pragma unroll
    for (int off = 32; off; off >>= 1) var += __shfl_xor(var, off, 64);
    const float rs = rsqrtf(var * (1.0f / DDIM) + 1e-5f);
    short8 ov;
#pragma unroll
    for (int i = 0; i < 8; ++i) {
        const int d0 = lane * 8 + i;
        ov[i] = (short)f2bf((xv[i] - mu) * rs * g[d0] + bt[d0]);
    }
    *(short8*)&o[base] = ov;
}

// ---------------------------------------------------------------------------
extern "C" void kernel_launch(void* const* d_in, const int* in_sizes, int n_in,
                              void* d_out, int out_size, void* d_ws, size_t ws_size,
                              hipStream_t stream)
{
    const float* item = (const float*)d_in[0];
    const float* user = (const float*)d_in[1];
    const int*   resp = (const int*)d_in[2];
    const float* Wq = (const float*)d_in[3];  const float* bq = (const float*)d_in[4];
    const float* Wk = (const float*)d_in[5];  const float* bk = (const float*)d_in[6];
    const float* Wv = (const float*)d_in[7];  const float* bv = (const float*)d_in[8];
    const float* Wo = (const float*)d_in[9];  const float* bo = (const float*)d_in[10];
    const float* lng = (const float*)d_in[11]; const float* lnb = (const float*)d_in[12];
    const float* W1 = (const float*)d_in[13]; const float* b1 = (const float*)d_in[14];
    const float* W2 = (const float*)d_in[15]; const float* b2 = (const float*)d_in[16];
    float* out = (float*)d_out;

    char* p = (char*)d_ws;
    auto alloc = [&](size_t bytes) { char* r = p; p += (bytes + 255) & ~(size_t)255; return r; };
    const size_t NITEM = (size_t)BATCH * NROWS * EDIM;
    const size_t NW    = (size_t)DDIM * DDIM;
    const size_t NQ    = (size_t)BATCH * HEADS * LFULL * HD;
    const size_t NC    = (size_t)BATCH * HEADS * CMAX * HD;
    const size_t NMD   = (size_t)MTOT * DDIM;
    const size_t PAD   = 8192;

    unsigned short* itemb  = (unsigned short*)alloc(NITEM * 2);
    unsigned short* Wqkvb  = (unsigned short*)alloc((size_t)NQKV * EDIM * 2);
    unsigned short* Wob    = (unsigned short*)alloc(NW * 2);
    unsigned short* W1b    = (unsigned short*)alloc(NW * 2);
    unsigned short* qb     = (unsigned short*)alloc(NQ * 2 + PAD);
    unsigned short* kcb    = (unsigned short*)alloc(NC * 2 + PAD);
    unsigned short* vcb    = (unsigned short*)alloc(NC * 2 + PAD);
    unsigned short* aob    = (unsigned short*)alloc(NMD * 2);
    unsigned short* fb16   = (unsigned short*)alloc(NMD * 2);
    float* uball = (float*)alloc((size_t)BATCH * NQKV * 4);
    float* part  = (float*)alloc((size_t)MTOT * 8 * 4);
    int* cidx    = (int*)alloc((size_t)BATCH * 512 * 4);
    int* cnt     = (int*)alloc((size_t)BATCH * 32 * 4);

    cvt_kernel<<<dim3((NITEM / 4 + 255) / 256), 256, 0, stream>>>(item, itemb, NITEM / 4);
    packqkv_kernel<<<dim3(DDIM * EDIM / 4 / 256, 3), 256, 0, stream>>>(Wq, Wk, Wv, Wqkvb);
    Cvt2 c2;
    c2.s[0] = Wo; c2.s[1] = W1; c2.d[0] = Wob; c2.d[1] = W1b;
    cvt2_kernel<<<dim3(NW / 4 / 256, 2), 256, 0, stream>>>(c2, NW / 4);

    compact_kernel<<<dim3(BATCH), 64, 0, stream>>>(resp, cidx, cnt);

    user_bias_kernel<<<dim3(BATCH, 3), 256, 0, stream>>>(
        user, Wq, bq, Wk, bk, Wv, bv, uball, qb, kcb, vcb);

    gemm_qkv<<<dim3(NQKV / 128, MTOT / 128), 256, 0, stream>>>(
        itemb, Wqkvb, uball, cidx, qb, kcb, vcb);

    attn_mfma<<<dim3(SLATES, HEADS, BATCH), 256, 0, stream>>>(qb, kcb, vcb, cnt, aob);

    dim3 gg(DDIM / 128, MTOT / 128);
    gemm_bf16<1><<<gg, 256, 0, stream>>>(aob, Wob, bo, fb16, nullptr, nullptr);
    ln_kernel<<<dim3(MTOT / 4), 256, 0, stream>>>(fb16, lng, lnb, aob);
    gemm_bf16<2><<<gg, 256, 0, stream>>>(aob, W1b, b1, nullptr, W2, part);
    w2red_kernel<<<dim3((MTOT + 255) / 256), 256, 0, stream>>>(part, b2, out);
}

// Round 11
// 280.705 us; speedup vs baseline: 1.5275x; 1.0522x over previous
//
#include <hip/hip_runtime.h>
#include <math.h>

#define BATCH 64
#define SLATES 25
#define KPS 20
#define EDIM 256
#define DDIM 512
#define HEADS 8
#define HD 64
#define LFULL 501
#define NROWS 500
#define MTOT (BATCH*NROWS)   // 32000
#define CMAX 512             // compacted key capacity
#define NQKV 1536            // packed q|k|v output dim
#define RB 32                // attn rows per block
#define NRB ((NROWS + RB - 1) / RB)   // 16

typedef __attribute__((ext_vector_type(8))) short short8;
typedef __attribute__((ext_vector_type(4))) float f32x4;

__device__ __forceinline__ unsigned short f2bf(float x) {
    unsigned int u = __builtin_bit_cast(unsigned int, x);
    u = (u + 0x7FFFu + ((u >> 16) & 1u)) >> 16;
    return (unsigned short)u;
}
__device__ __forceinline__ float bf2f(unsigned short s) {
    unsigned int u = ((unsigned int)s) << 16;
    return __builtin_bit_cast(float, u);
}
__device__ __forceinline__ float gelu_exact(float x) {
    return 0.5f * x * (1.0f + erff(x * 0.70710678118654752440f));
}
__device__ __forceinline__ void gload16(const void* g, void* l) {
    __builtin_amdgcn_global_load_lds(
        (const __attribute__((address_space(1))) void*)g,
        (__attribute__((address_space(3))) void*)l, 16, 0, 0);
}

// ---------------------------------------------------------------------------
// fp32 -> bf16 converts / weight packing
// ---------------------------------------------------------------------------
__global__ __launch_bounds__(256) void cvt_kernel(
    const float* __restrict__ src, unsigned short* __restrict__ dst, int n4)
{
    const int i = blockIdx.x * 256 + threadIdx.x;
    if (i >= n4) return;
    float4 v = ((const float4*)src)[i];
    ushort4 o;
    o.x = f2bf(v.x); o.y = f2bf(v.y); o.z = f2bf(v.z); o.w = f2bf(v.w);
    ((ushort4*)dst)[i] = o;
}

struct Cvt2 { const float* s[2]; unsigned short* d[2]; };
__global__ __launch_bounds__(256) void cvt2_kernel(Cvt2 a, int n4)
{
    const int i = blockIdx.x * 256 + threadIdx.x;
    if (i >= n4) return;
    const int y = blockIdx.y;
    float4 v = ((const float4*)a.s[y])[i];
    ushort4 o;
    o.x = f2bf(v.x); o.y = f2bf(v.y); o.z = f2bf(v.z); o.w = f2bf(v.w);
    ((ushort4*)a.d[y])[i] = o;
}

// Pack [Wq;Wk;Wv][:, 0:256] -> (1536 x 256) bf16
__global__ __launch_bounds__(256) void packqkv_kernel(
    const float* __restrict__ Wq, const float* __restrict__ Wk,
    const float* __restrict__ Wv, unsigned short* __restrict__ dst)
{
    const int y = blockIdx.y;
    const float* W = (y == 0) ? Wq : (y == 1) ? Wk : Wv;
    const int i = blockIdx.x * 256 + threadIdx.x;
    const int row = i >> 6, c4 = (i & 63) * 4;
    float4 v = *(const float4*)&W[(size_t)row * DDIM + c4];
    ushort4 o;
    o.x = f2bf(v.x); o.y = f2bf(v.y); o.z = f2bf(v.z); o.w = f2bf(v.w);
    *(ushort4*)&dst[((size_t)y * DDIM + row) * EDIM + c4] = o;
}

// ---------------------------------------------------------------------------
// Click compaction: one wave per batch.
// ---------------------------------------------------------------------------
__global__ __launch_bounds__(64) void compact_kernel(
    const int* __restrict__ resp, int* __restrict__ cidx, int* __restrict__ cnt)
{
    const int b = blockIdx.x, lane = threadIdx.x;
    int a[8]; int c = 0;
#pragma unroll
    for (int j = 0; j < 8; ++j) {
        const int l = lane * 8 + j;
        int al = 0;
        if (l == 0) al = 1;
        else if (l <= NROWS) al = (resp[(size_t)b * NROWS + l - 1] > 0) ? 1 : 0;
        a[j] = al; c += al;
    }
    int incl = c;
#pragma unroll
    for (int off = 1; off < 64; off <<= 1) {
        int t = __shfl_up(incl, off, 64);
        if (lane >= off) incl += t;
    }
    int run = incl - c;
#pragma unroll
    for (int j = 0; j < 8; ++j) {
        const int l = lane * 8 + j;
        if (l >= 1 && l <= 481 && (l % 20) == 1)
            cnt[b * 32 + (l - 1) / 20] = run;
        cidx[b * 512 + l] = a[j] ? run : -1;
        run += a[j];
    }
}

// ---------------------------------------------------------------------------
// Per-batch user bias tables (packed [B][1536]) + position-0 rows.
// ---------------------------------------------------------------------------
__global__ __launch_bounds__(256) void user_bias_kernel(
    const float* __restrict__ user,
    const float* __restrict__ Wq, const float* __restrict__ bq,
    const float* __restrict__ Wk, const float* __restrict__ bk,
    const float* __restrict__ Wv, const float* __restrict__ bv,
    float* __restrict__ uball,
    unsigned short* __restrict__ qb, unsigned short* __restrict__ kc,
    unsigned short* __restrict__ vc)
{
    const int b = blockIdx.x;
    const int y = blockIdx.y;
    const int tid = threadIdx.x;
    const float* W  = (y == 0) ? Wq : (y == 1) ? Wk : Wv;
    const float* bi = (y == 0) ? bq : (y == 1) ? bk : bv;

    __shared__ float us[EDIM];
    if (tid < EDIM) us[tid] = user[b * EDIM + tid];
    __syncthreads();
    for (int o = tid; o < DDIM; o += 256) {
        float s = bi[o];
        const float* wr = &W[(size_t)o * DDIM + EDIM];
#pragma unroll 4
        for (int e = 0; e < EDIM; ++e) s += us[e] * wr[e];
        uball[(size_t)b * NQKV + y * DDIM + o] = s;
        const int hh = o >> 6, dd = o & 63;
        const size_t bh = (size_t)b * HEADS + hh;
        if (y == 0)      qb[(bh * LFULL) * HD + dd] = f2bf(bi[o]);
        else if (y == 1) kc[(bh * CMAX) * HD + dd] = f2bf(bi[o]);
        else             vc[(bh * HD + dd) * CMAX] = f2bf(bi[o]);
    }
}

// ---------------------------------------------------------------------------
// Merged QKV GEMM: counted-vmcnt 3-buffer pipeline + LDS-bounce coalesced
// epilogue + XCD-chunked block swizzle. Grid = (12, 250) = 3000 blocks.
// ---------------------------------------------------------------------------
__global__ __launch_bounds__(256) void gemm_qkv(
    const unsigned short* __restrict__ A,
    const unsigned short* __restrict__ Wqkv,
    const float* __restrict__ uball, const int* __restrict__ cidx,
    unsigned short* __restrict__ oq, unsigned short* __restrict__ ok,
    unsigned short* __restrict__ ov)
{
    const int tid = threadIdx.x;
    // XCD-chunked bijective swizzle: 3000 blocks = 8 XCDs x 375
    const int lin = blockIdx.y * gridDim.x + blockIdx.x;
    const int vb  = (lin & 7) * 375 + (lin >> 3);
    const int n0 = (vb % 12) * 128;   // 0..1535
    const int m0 = (vb / 12) * 128;
    const int lane = tid & 63, wid = tid >> 6;
    const int wm = (wid & 1) * 64, wn = (wid >> 1) * 64;

    __shared__ __align__(16) unsigned short sm[24576];
    __shared__ int cids[128];
    auto As = [&](int buf) { return (unsigned short(*)[32])(sm + buf * 4096); };
    auto Ws = [&](int buf) { return (unsigned short(*)[32])(sm + 12288 + buf * 4096); };
    auto bounce = (unsigned short(*)[136])sm;

    f32x4 acc[4][4];
#pragma unroll
    for (int i = 0; i < 4; ++i)
#pragma unroll
        for (int j = 0; j < 4; ++j) acc[i][j] = (f32x4){0.f, 0.f, 0.f, 0.f};

    const unsigned short* gA0 = &A[(size_t)(m0 + wid * 16 + (lane >> 2)) * EDIM + (lane & 3) * 8];
    const unsigned short* gA1 = gA0 + (size_t)64 * EDIM;
    const unsigned short* gW0 = &Wqkv[(size_t)(n0 + wid * 16 + (lane >> 2)) * EDIM + (lane & 3) * 8];
    const unsigned short* gW1 = gW0 + (size_t)64 * EDIM;
    const int frow = lane & 15, fk = (lane >> 4) * 8;

    auto stage = [&](int buf, int k0) {
        gload16(gA0 + k0, &As(buf)[wid * 16][0]);
        gload16(gA1 + k0, &As(buf)[64 + wid * 16][0]);
        gload16(gW0 + k0, &Ws(buf)[wid * 16][0]);
        gload16(gW1 + k0, &Ws(buf)[64 + wid * 16][0]);
    };
    stage(0, 0);
    stage(1, 32);

    const int nst = EDIM / 32;   // 8
    for (int t = 0; t < nst; ++t) {
        const int cur = t % 3;
        if (t < nst - 1) asm volatile("s_waitcnt vmcnt(4)" ::: "memory");
        else             asm volatile("s_waitcnt vmcnt(0)" ::: "memory");
        __builtin_amdgcn_s_barrier();
        __builtin_amdgcn_sched_barrier(0);
        short8 af[4], wf[4];
#pragma unroll
        for (int mi = 0; mi < 4; ++mi)
            af[mi] = *(const short8*)&As(cur)[wm + mi * 16 + frow][fk];
#pragma unroll
        for (int ni = 0; ni < 4; ++ni)
            wf[ni] = *(const short8*)&Ws(cur)[wn + ni * 16 + frow][fk];
#pragma unroll
        for (int mi = 0; mi < 4; ++mi)
#pragma unroll
            for (int ni = 0; ni < 4; ++ni)
                acc[mi][ni] = __builtin_amdgcn_mfma_f32_16x16x32_bf16(
                    af[mi], wf[ni], acc[mi][ni], 0, 0, 0);
        if (t + 2 < nst) stage((t + 2) % 3, (t + 2) * 32);
    }

    // ---- epilogue: bounce through LDS for coalesced stores ----
    const int z = n0 >> 9;               // 0=q 1=k 2=v
    const int b0 = m0 / NROWS;
    const int split = (b0 + 1) * NROWS;
    const int b1 = (split <= m0 + 127) ? b0 + 1 : b0;
    float ub0[4], ub1[4];
#pragma unroll
    for (int ni = 0; ni < 4; ++ni) {
        const int np = n0 + wn + ni * 16 + frow;
        ub0[ni] = uball[(size_t)b0 * NQKV + np];
        ub1[ni] = uball[(size_t)b1 * NQKV + np];
    }
    __syncthreads();
    if (z != 0 && tid < 128) {
        const int m = m0 + tid;
        const int b = (m >= split) ? b1 : b0;
        cids[tid] = cidx[b * 512 + (m - b * NROWS + 1)];
    }
#pragma unroll
    for (int mi = 0; mi < 4; ++mi)
#pragma unroll
        for (int r = 0; r < 4; ++r) {
            const int ml = wm + mi * 16 + (lane >> 4) * 4 + r;
            const bool hi = (m0 + ml >= split);
#pragma unroll
            for (int ni = 0; ni < 4; ++ni)
                bounce[ml][wn + ni * 16 + frow] =
                    f2bf(acc[mi][ni][r] + (hi ? ub1[ni] : ub0[ni]));
        }
    __syncthreads();

    const int h0 = (n0 & 511) >> 6;
    if (z == 0) {
        const int row = tid >> 1, half = tid & 1;
        const int m = m0 + row;
        const int b = (m >= split) ? b1 : b0;
        const int l = m - b * NROWS + 1;
        unsigned short* dst = &oq[(((size_t)b * HEADS + h0 + half) * LFULL + l) * HD];
        const unsigned short* src = &bounce[row][half * 64];
#pragma unroll
        for (int j = 0; j < 8; ++j)
            *(uint4*)(dst + j * 8) = *(const uint4*)(src + j * 8);
    } else if (z == 1) {
        const int row = tid >> 1, half = tid & 1;
        const int c = cids[row];
        if (c >= 0) {
            const int m = m0 + row;
            const int b = (m >= split) ? b1 : b0;
            unsigned short* dst = &ok[(((size_t)b * HEADS + h0 + half) * CMAX + c) * HD];
            const unsigned short* src = &bounce[row][half * 64];
#pragma unroll
            for (int j = 0; j < 8; ++j)
                *(uint4*)(dst + j * 8) = *(const uint4*)(src + j * 8);
        }
    } else {
        const int col = tid & 127, mh = tid >> 7;
        const int hh = h0 + (col >> 6), dd = col & 63;
        for (int mm = 0; mm < 64; ++mm) {
            const int row = mh * 64 + mm;
            const int c = cids[row];
            if (c >= 0) {
                const int m = m0 + row;
                const int b = (m >= split) ? b1 : b0;
                ov[((size_t)b * HEADS + hh) * (size_t)(HD * CMAX)
                   + (size_t)dd * CMAX + c] = bounce[row][col];
            }
        }
    }
}

// ---------------------------------------------------------------------------
// Generic bf16 GEMM (counted-vmcnt 3-buffer) + XCD swizzle (1000 = 8 x 125).
// MODE 1: +bias, bf16 out. MODE 2: +bias, gelu, dot W2 -> 8 partials/row.
// ---------------------------------------------------------------------------
template <int MODE>
__global__ __launch_bounds__(256) void gemm_bf16(
    const unsigned short* __restrict__ A,
    const unsigned short* __restrict__ W,
    const float* __restrict__ bias, void* __restrict__ outp,
    const float* __restrict__ W2, float* __restrict__ part)
{
    const int tid = threadIdx.x;
    const int lin = blockIdx.y * gridDim.x + blockIdx.x;
    const int vb  = (lin & 7) * 125 + (lin >> 3);
    const int n0 = (vb % 4) * 128;
    const int m0 = (vb / 4) * 128;
    const int lane = tid & 63, wid = tid >> 6;
    const int wm = (wid & 1) * 64, wn = (wid >> 1) * 64;

    __shared__ unsigned short As[3][128][32];
    __shared__ unsigned short Ws[3][128][32];

    f32x4 acc[4][4];
#pragma unroll
    for (int i = 0; i < 4; ++i)
#pragma unroll
        for (int j = 0; j < 4; ++j) acc[i][j] = (f32x4){0.f, 0.f, 0.f, 0.f};

    const unsigned short* gA0 = &A[(size_t)(m0 + wid * 16 + (lane >> 2)) * DDIM + (lane & 3) * 8];
    const unsigned short* gA1 = gA0 + (size_t)64 * DDIM;
    const unsigned short* gW0 = &W[(size_t)(n0 + wid * 16 + (lane >> 2)) * DDIM + (lane & 3) * 8];
    const unsigned short* gW1 = gW0 + (size_t)64 * DDIM;
    const int frow = lane & 15, fk = (lane >> 4) * 8;

    auto stage = [&](int buf, int k0) {
        gload16(gA0 + k0, &As[buf][wid * 16][0]);
        gload16(gA1 + k0, &As[buf][64 + wid * 16][0]);
        gload16(gW0 + k0, &Ws[buf][wid * 16][0]);
        gload16(gW1 + k0, &Ws[buf][64 + wid * 16][0]);
    };
    stage(0, 0);
    stage(1, 32);

    const int nst = DDIM / 32;   // 16
    for (int t = 0; t < nst; ++t) {
        const int cur = t % 3;
        if (t < nst - 1) asm volatile("s_waitcnt vmcnt(4)" ::: "memory");
        else             asm volatile("s_waitcnt vmcnt(0)" ::: "memory");
        __builtin_amdgcn_s_barrier();
        __builtin_amdgcn_sched_barrier(0);
        short8 af[4], wf[4];
#pragma unroll
        for (int mi = 0; mi < 4; ++mi)
            af[mi] = *(const short8*)&As[cur][wm + mi * 16 + frow][fk];
#pragma unroll
        for (int ni = 0; ni < 4; ++ni)
            wf[ni] = *(const short8*)&Ws[cur][wn + ni * 16 + frow][fk];
#pragma unroll
        for (int mi = 0; mi < 4; ++mi)
#pragma unroll
            for (int ni = 0; ni < 4; ++ni)
                acc[mi][ni] = __builtin_amdgcn_mfma_f32_16x16x32_bf16(
                    af[mi], wf[ni], acc[mi][ni], 0, 0, 0);
        if (t + 2 < nst) stage((t + 2) % 3, (t + 2) * 32);
    }

    if (MODE == 1) {
#pragma unroll
        for (int mi = 0; mi < 4; ++mi)
#pragma unroll
            for (int ni = 0; ni < 4; ++ni) {
                const int n = n0 + wn + ni * 16 + frow;
                const float bv = bias[n];
#pragma unroll
                for (int r = 0; r < 4; ++r) {
                    const int m = m0 + wm + mi * 16 + (lane >> 4) * 4 + r;
                    ((unsigned short*)outp)[(size_t)m * DDIM + n] =
                        f2bf(acc[mi][ni][r] + bv);
                }
            }
    } else {
        float w2v[4], bv4[4];
#pragma unroll
        for (int ni = 0; ni < 4; ++ni) {
            const int n = n0 + wn + ni * 16 + frow;
            w2v[ni] = W2[n];
            bv4[ni] = bias[n];
        }
        float ps[4][4];
#pragma unroll
        for (int mi = 0; mi < 4; ++mi)
#pragma unroll
            for (int r = 0; r < 4; ++r) ps[mi][r] = 0.f;
#pragma unroll
        for (int mi = 0; mi < 4; ++mi)
#pragma unroll
            for (int ni = 0; ni < 4; ++ni)
#pragma unroll
                for (int r = 0; r < 4; ++r)
                    ps[mi][r] += gelu_exact(acc[mi][ni][r] + bv4[ni]) * w2v[ni];
        const int slot = (n0 >> 7) * 2 + (wn >> 6);
#pragma unroll
        for (int mi = 0; mi < 4; ++mi)
#pragma unroll
            for (int r = 0; r < 4; ++r) {
                float s = ps[mi][r];
                s += __shfl_xor(s, 1, 64);
                s += __shfl_xor(s, 2, 64);
                s += __shfl_xor(s, 4, 64);
                s += __shfl_xor(s, 8, 64);
                if (frow == 0) {
                    const int m = m0 + wm + mi * 16 + (lane >> 4) * 4 + r;
                    part[(size_t)m * 8 + slot] = s;
                }
            }
    }
}

// ---------------------------------------------------------------------------
// Final reduction: out[m] = b2 + sum of 8 partials.
// ---------------------------------------------------------------------------
__global__ __launch_bounds__(256) void w2red_kernel(
    const float* __restrict__ part, const float* __restrict__ b2,
    float* __restrict__ out)
{
    const int m = blockIdx.x * 256 + threadIdx.x;
    if (m >= MTOT) return;
    const float* p = part + (size_t)m * 8;
    float s = b2[0];
#pragma unroll
    for (int i = 0; i < 8; ++i) s += p[i];
    out[m] = s;
}

// ---------------------------------------------------------------------------
// Attention v7: row-packed 32-row blocks (full row utilization), per-row
// key-count mask, fused exp, XCD-chunked swizzle (8192 = 8 x 1024).
// ---------------------------------------------------------------------------
__global__ __launch_bounds__(256) void attn_mfma(
    const unsigned short* __restrict__ qx, const unsigned short* __restrict__ kc,
    const unsigned short* __restrict__ vc, const int* __restrict__ cnt,
    unsigned short* __restrict__ outb)
{
    // swizzle: 1024 consecutive lin = 64 (b,h) panels per XCD chunk
    const int lin = blockIdx.x + NRB * (blockIdx.y + HEADS * blockIdx.z);
    const int vbk = (lin & 7) * (NRB * HEADS * BATCH / 8) + (lin >> 3);
    const int rbk = vbk % NRB;
    const int h   = (vbk / NRB) % HEADS;
    const int b   = vbk / (NRB * HEADS);
    const int g0  = rbk * RB;          // first 0-based output row of block

    const int tid = threadIdx.x, lane = tid & 63, w = tid >> 6;

    __shared__ __align__(16) unsigned short scb[RB][520];  // bf16 P
    __shared__ float rsw[4][RB];                           // per-wave row sums
    __shared__ int snck[RB];                               // per-row key count

    const int frow = lane & 15, fk = (lane >> 4) * 8;
    const size_t bh = (size_t)b * HEADS + h;
    const unsigned short* kbase = kc + bh * (CMAX * HD);
    const unsigned short* vbase = vc + bh * (HD * CMAX);

    if (tid < RB) {
        const int s = (g0 + tid >= NROWS ? NROWS - 1 : g0 + tid) / KPS;
        snck[tid] = cnt[b * 32 + s];
    }

    // Q fragments: rows g0 + mi*16 + frow (l = row+1)
    short8 qf[2][2];
#pragma unroll
    for (int mi = 0; mi < 2; ++mi) {
        const int qrow = g0 + mi * 16 + frow;
#pragma unroll
        for (int ks = 0; ks < 2; ++ks) {
            short8 v = {};
            if (qrow < NROWS)
                v = *(const short8*)&qx[(bh * LFULL + qrow + 1) * HD + ks * 32 + fk];
            qf[mi][ks] = v;
        }
    }
    __syncthreads();   // snck visible

    // per-lane key counts for its 8 accumulator rows
    int nck8[2][4];
#pragma unroll
    for (int mi = 0; mi < 2; ++mi)
#pragma unroll
        for (int r = 0; r < 4; ++r)
            nck8[mi][r] = snck[mi * 16 + (lane >> 4) * 4 + r];
    const int nmax = snck[RB - 1];     // cnt is monotone in slate
    const int NT = (nmax + 63) >> 6;

    // ---- QK^T + fused exp + row-sum partials (barrier-free) ----
    f32x4 rsum[2];
    rsum[0] = (f32x4){0.f, 0.f, 0.f, 0.f};
    rsum[1] = (f32x4){0.f, 0.f, 0.f, 0.f};
    for (int t = 0; t < NT; ++t) {
        const int key = (t << 6) + w * 16 + frow;
        const unsigned short* kr = kbase + (size_t)key * HD;
        const short8 kf0 = *(const short8*)(kr + fk);
        const short8 kf1 = *(const short8*)(kr + 32 + fk);
        f32x4 s2[2];
#pragma unroll
        for (int mi = 0; mi < 2; ++mi) {
            s2[mi] = (f32x4){0.f, 0.f, 0.f, 0.f};
            s2[mi] = __builtin_amdgcn_mfma_f32_16x16x32_bf16(qf[mi][0], kf0, s2[mi], 0, 0, 0);
            s2[mi] = __builtin_amdgcn_mfma_f32_16x16x32_bf16(qf[mi][1], kf1, s2[mi], 0, 0, 0);
        }
#pragma unroll
        for (int mi = 0; mi < 2; ++mi)
#pragma unroll
            for (int r = 0; r < 4; ++r) {
                const int row = mi * 16 + (lane >> 4) * 4 + r;
                const float p = (key < nck8[mi][r]) ? __expf(s2[mi][r] * 0.125f) : 0.f;
                rsum[mi][r] += p;
                scb[row][key] = f2bf(p);
            }
    }
#pragma unroll
    for (int mi = 0; mi < 2; ++mi)
#pragma unroll
        for (int r = 0; r < 4; ++r) {
            float v = rsum[mi][r];
            v += __shfl_xor(v, 1, 64);
            v += __shfl_xor(v, 2, 64);
            v += __shfl_xor(v, 4, 64);
            v += __shfl_xor(v, 8, 64);
            if (frow == 0)
                rsw[w][mi * 16 + (lane >> 4) * 4 + r] = v;
        }
    __syncthreads();

    // ---- PV (barrier-free; wave w owns dims w*16..w*16+15) ----
    f32x4 po[2];
    po[0] = (f32x4){0.f, 0.f, 0.f, 0.f};
    po[1] = (f32x4){0.f, 0.f, 0.f, 0.f};
    const unsigned short* vrow = vbase + (size_t)(w * 16 + frow) * CMAX;
    for (int t = 0; t < NT; ++t) {
#pragma unroll
        for (int ks = 0; ks < 2; ++ks) {
            const int kb0 = (t << 6) + ks * 32 + fk;
            const short8 vf = *(const short8*)(vrow + kb0);  // P=0 masks garbage
#pragma unroll
            for (int mi = 0; mi < 2; ++mi) {
                const short8 pf = *(const short8*)&scb[mi * 16 + frow][kb0];
                po[mi] = __builtin_amdgcn_mfma_f32_16x16x32_bf16(pf, vf, po[mi], 0, 0, 0);
            }
        }
    }

#pragma unroll
    for (int mi = 0; mi < 2; ++mi)
#pragma unroll
        for (int r = 0; r < 4; ++r) {
            const int row = mi * 16 + (lane >> 4) * 4 + r;
            const int m = g0 + row;
            if (m < NROWS) {
                const float inv = 1.0f / (rsw[0][row] + rsw[1][row]
                                        + rsw[2][row] + rsw[3][row]);
                outb[((size_t)b * NROWS + m) * DDIM
                     + h * HD + w * 16 + frow] = f2bf(po[mi][r] * inv);
            }
        }
}

// ---------------------------------------------------------------------------
// LayerNorm bf16 -> bf16. One wave per row, 16B/lane loads.
// ---------------------------------------------------------------------------
__global__ __launch_bounds__(256) void ln_kernel(
    const unsigned short* __restrict__ f, const float* __restrict__ g,
    const float* __restrict__ bt, unsigned short* __restrict__ o)
{
    const int row = blockIdx.x * 4 + (threadIdx.x >> 6);
    const int lane = threadIdx.x & 63;
    const size_t base = (size_t)row * DDIM + lane * 8;
    short8 v = *(const short8*)&f[base];
    float xv[8];
    float s = 0.f;
#pragma unroll
    for (int i = 0; i < 8; ++i) { xv[i] = bf2f((unsigned short)v[i]); s += xv[i]; }
#pragma unroll
    for (int off = 32; off; off >>= 1) s += __shfl_xor(s, off, 64);
    const float mu = s * (1.0f / DDIM);
    float var = 0.f;
#pragma unroll
    for (int i = 0; i < 8; ++i) { const float d0 = xv[i] - mu; var += d0 * d0; }
#pragma unroll
    for (int off = 32; off; off >>= 1) var += __shfl_xor(var, off, 64);
    const float rs = rsqrtf(var * (1.0f / DDIM) + 1e-5f);
    short8 ov;
#pragma unroll
    for (int i = 0; i < 8; ++i) {
        const int d0 = lane * 8 + i;
        ov[i] = (short)f2bf((xv[i] - mu) * rs * g[d0] + bt[d0]);
    }
    *(short8*)&o[base] = ov;
}

// ---------------------------------------------------------------------------
extern "C" void kernel_launch(void* const* d_in, const int* in_sizes, int n_in,
                              void* d_out, int out_size, void* d_ws, size_t ws_size,
                              hipStream_t stream)
{
    const float* item = (const float*)d_in[0];
    const float* user = (const float*)d_in[1];
    const int*   resp = (const int*)d_in[2];
    const float* Wq = (const float*)d_in[3];  const float* bq = (const float*)d_in[4];
    const float* Wk = (const float*)d_in[5];  const float* bk = (const float*)d_in[6];
    const float* Wv = (const float*)d_in[7];  const float* bv = (const float*)d_in[8];
    const float* Wo = (const float*)d_in[9];  const float* bo = (const float*)d_in[10];
    const float* lng = (const float*)d_in[11]; const float* lnb = (const float*)d_in[12];
    const float* W1 = (const float*)d_in[13]; const float* b1 = (const float*)d_in[14];
    const float* W2 = (const float*)d_in[15]; const float* b2 = (const float*)d_in[16];
    float* out = (float*)d_out;

    char* p = (char*)d_ws;
    auto alloc = [&](size_t bytes) { char* r = p; p += (bytes + 255) & ~(size_t)255; return r; };
    const size_t NITEM = (size_t)BATCH * NROWS * EDIM;
    const size_t NW    = (size_t)DDIM * DDIM;
    const size_t NQ    = (size_t)BATCH * HEADS * LFULL * HD;
    const size_t NC    = (size_t)BATCH * HEADS * CMAX * HD;
    const size_t NMD   = (size_t)MTOT * DDIM;
    const size_t PAD   = 8192;

    unsigned short* itemb  = (unsigned short*)alloc(NITEM * 2);
    unsigned short* Wqkvb  = (unsigned short*)alloc((size_t)NQKV * EDIM * 2);
    unsigned short* Wob    = (unsigned short*)alloc(NW * 2);
    unsigned short* W1b    = (unsigned short*)alloc(NW * 2);
    unsigned short* qb     = (unsigned short*)alloc(NQ * 2 + PAD);
    unsigned short* kcb    = (unsigned short*)alloc(NC * 2 + PAD);
    unsigned short* vcb    = (unsigned short*)alloc(NC * 2 + PAD);
    unsigned short* aob    = (unsigned short*)alloc(NMD * 2);
    unsigned short* fb16   = (unsigned short*)alloc(NMD * 2);
    float* uball = (float*)alloc((size_t)BATCH * NQKV * 4);
    float* part  = (float*)alloc((size_t)MTOT * 8 * 4);
    int* cidx    = (int*)alloc((size_t)BATCH * 512 * 4);
    int* cnt     = (int*)alloc((size_t)BATCH * 32 * 4);

    cvt_kernel<<<dim3((NITEM / 4 + 255) / 256), 256, 0, stream>>>(item, itemb, NITEM / 4);
    packqkv_kernel<<<dim3(DDIM * EDIM / 4 / 256, 3), 256, 0, stream>>>(Wq, Wk, Wv, Wqkvb);
    Cvt2 c2;
    c2.s[0] = Wo; c2.s[1] = W1; c2.d[0] = Wob; c2.d[1] = W1b;
    cvt2_kernel<<<dim3(NW / 4 / 256, 2), 256, 0, stream>>>(c2, NW / 4);

    compact_kernel<<<dim3(BATCH), 64, 0, stream>>>(resp, cidx, cnt);

    user_bias_kernel<<<dim3(BATCH, 3), 256, 0, stream>>>(
        user, Wq, bq, Wk, bk, Wv, bv, uball, qb, kcb, vcb);

    gemm_qkv<<<dim3(NQKV / 128, MTOT / 128), 256, 0, stream>>>(
        itemb, Wqkvb, uball, cidx, qb, kcb, vcb);

    attn_mfma<<<dim3(NRB, HEADS, BATCH), 256, 0, stream>>>(qb, kcb, vcb, cnt, aob);

    dim3 gg(DDIM / 128, MTOT / 128);
    gemm_bf16<1><<<gg, 256, 0, stream>>>(aob, Wob, bo, fb16, nullptr, nullptr);
    ln_kernel<<<dim3(MTOT / 4), 256, 0, stream>>>(fb16, lng, lnb, aob);
    gemm_bf16<2><<<gg, 256, 0, stream>>>(aob, W1b, b1, nullptr, W2, part);
    w2red_kernel<<<dim3((MTOT + 255) / 256), 256, 0, stream>>>(part, b2, out);
}

// Round 12
// 257.521 us; speedup vs baseline: 1.6650x; 1.0900x over previous
//
#include <hip/hip_runtime.h>
#include <math.h>

#define BATCH 64
#define SLATES 25
#define KPS 20
#define EDIM 256
#define DDIM 512
#define HEADS 8
#define HD 64
#define LFULL 501
#define NROWS 500
#define MTOT (BATCH*NROWS)   // 32000
#define CMAX 512             // compacted key capacity
#define NQKV 1536            // packed q|k|v output dim
#define RB 32                // attn rows per block
#define NRB ((NROWS + RB - 1) / RB)   // 16

typedef __attribute__((ext_vector_type(8))) short short8;
typedef __attribute__((ext_vector_type(4))) float f32x4;

__device__ __forceinline__ unsigned short f2bf(float x) {
    unsigned int u = __builtin_bit_cast(unsigned int, x);
    u = (u + 0x7FFFu + ((u >> 16) & 1u)) >> 16;
    return (unsigned short)u;
}
__device__ __forceinline__ float bf2f(unsigned short s) {
    unsigned int u = ((unsigned int)s) << 16;
    return __builtin_bit_cast(float, u);
}
__device__ __forceinline__ float gelu_exact(float x) {
    return 0.5f * x * (1.0f + erff(x * 0.70710678118654752440f));
}
__device__ __forceinline__ void gload16(const void* g, void* l) {
    __builtin_amdgcn_global_load_lds(
        (const __attribute__((address_space(1))) void*)g,
        (__attribute__((address_space(3))) void*)l, 16, 0, 0);
}

// ---------------------------------------------------------------------------
// fp32 -> bf16 convert / weight packing
// ---------------------------------------------------------------------------
__global__ __launch_bounds__(256) void cvt_kernel(
    const float* __restrict__ src, unsigned short* __restrict__ dst, int n4)
{
    const int i = blockIdx.x * 256 + threadIdx.x;
    if (i >= n4) return;
    float4 v = ((const float4*)src)[i];
    ushort4 o;
    o.x = f2bf(v.x); o.y = f2bf(v.y); o.z = f2bf(v.z); o.w = f2bf(v.w);
    ((ushort4*)dst)[i] = o;
}

// Pack [Wq;Wk;Wv][:, 0:256] -> (1536 x 256) bf16
__global__ __launch_bounds__(256) void packqkv_kernel(
    const float* __restrict__ Wq, const float* __restrict__ Wk,
    const float* __restrict__ Wv, unsigned short* __restrict__ dst)
{
    const int y = blockIdx.y;
    const float* W = (y == 0) ? Wq : (y == 1) ? Wk : Wv;
    const int i = blockIdx.x * 256 + threadIdx.x;
    const int row = i >> 6, c4 = (i & 63) * 4;
    float4 v = *(const float4*)&W[(size_t)row * DDIM + c4];
    ushort4 o;
    o.x = f2bf(v.x); o.y = f2bf(v.y); o.z = f2bf(v.z); o.w = f2bf(v.w);
    *(ushort4*)&dst[((size_t)y * DDIM + row) * EDIM + c4] = o;
}

// ---------------------------------------------------------------------------
// LN fold prep: W1g[n,k] = W1[n,k]*g[k] (bf16); c1c2[n] = (sum lnb*W1, sum g*W1)
// One wave per n-row.
// ---------------------------------------------------------------------------
__global__ __launch_bounds__(256) void w1prep_kernel(
    const float* __restrict__ W1, const float* __restrict__ g,
    const float* __restrict__ lnb, unsigned short* __restrict__ W1g,
    float2* __restrict__ c1c2)
{
    const int row = blockIdx.x * 4 + (threadIdx.x >> 6);
    const int lane = threadIdx.x & 63;
    float c1 = 0.f, c2 = 0.f;
#pragma unroll
    for (int i = 0; i < 8; ++i) {
        const int k = lane + i * 64;
        const float w = W1[(size_t)row * DDIM + k];
        const float gv = g[k];
        c1 += w * lnb[k];
        c2 += w * gv;
        W1g[(size_t)row * DDIM + k] = f2bf(w * gv);
    }
#pragma unroll
    for (int off = 32; off; off >>= 1) {
        c1 += __shfl_xor(c1, off, 64);
        c2 += __shfl_xor(c2, off, 64);
    }
    if (lane == 0) c1c2[row] = make_float2(c1, c2);
}

// ---------------------------------------------------------------------------
// Click compaction: one wave per batch.
// ---------------------------------------------------------------------------
__global__ __launch_bounds__(64) void compact_kernel(
    const int* __restrict__ resp, int* __restrict__ cidx, int* __restrict__ cnt)
{
    const int b = blockIdx.x, lane = threadIdx.x;
    int a[8]; int c = 0;
#pragma unroll
    for (int j = 0; j < 8; ++j) {
        const int l = lane * 8 + j;
        int al = 0;
        if (l == 0) al = 1;
        else if (l <= NROWS) al = (resp[(size_t)b * NROWS + l - 1] > 0) ? 1 : 0;
        a[j] = al; c += al;
    }
    int incl = c;
#pragma unroll
    for (int off = 1; off < 64; off <<= 1) {
        int t = __shfl_up(incl, off, 64);
        if (lane >= off) incl += t;
    }
    int run = incl - c;
#pragma unroll
    for (int j = 0; j < 8; ++j) {
        const int l = lane * 8 + j;
        if (l >= 1 && l <= 481 && (l % 20) == 1)
            cnt[b * 32 + (l - 1) / 20] = run;
        cidx[b * 512 + l] = a[j] ? run : -1;
        run += a[j];
    }
}

// ---------------------------------------------------------------------------
// Per-batch user bias tables (packed [B][1536]) + position-0 rows.
// ---------------------------------------------------------------------------
__global__ __launch_bounds__(256) void user_bias_kernel(
    const float* __restrict__ user,
    const float* __restrict__ Wq, const float* __restrict__ bq,
    const float* __restrict__ Wk, const float* __restrict__ bk,
    const float* __restrict__ Wv, const float* __restrict__ bv,
    float* __restrict__ uball,
    unsigned short* __restrict__ qb, unsigned short* __restrict__ kc,
    unsigned short* __restrict__ vc)
{
    const int b = blockIdx.x;
    const int y = blockIdx.y;
    const int tid = threadIdx.x;
    const float* W  = (y == 0) ? Wq : (y == 1) ? Wk : Wv;
    const float* bi = (y == 0) ? bq : (y == 1) ? bk : bv;

    __shared__ float us[EDIM];
    if (tid < EDIM) us[tid] = user[b * EDIM + tid];
    __syncthreads();
    for (int o = tid; o < DDIM; o += 256) {
        float s = bi[o];
        const float* wr = &W[(size_t)o * DDIM + EDIM];
#pragma unroll 4
        for (int e = 0; e < EDIM; ++e) s += us[e] * wr[e];
        uball[(size_t)b * NQKV + y * DDIM + o] = s;
        const int hh = o >> 6, dd = o & 63;
        const size_t bh = (size_t)b * HEADS + hh;
        if (y == 0)      qb[(bh * LFULL) * HD + dd] = f2bf(bi[o]);
        else if (y == 1) kc[(bh * CMAX) * HD + dd] = f2bf(bi[o]);
        else             vc[(bh * HD + dd) * CMAX] = f2bf(bi[o]);
    }
}

// ---------------------------------------------------------------------------
// Merged QKV GEMM: counted-vmcnt 3-buffer pipeline + LDS-bounce coalesced
// epilogue + XCD-chunked block swizzle. Grid = (12, 250) = 3000 blocks.
// ---------------------------------------------------------------------------
__global__ __launch_bounds__(256) void gemm_qkv(
    const unsigned short* __restrict__ A,
    const unsigned short* __restrict__ Wqkv,
    const float* __restrict__ uball, const int* __restrict__ cidx,
    unsigned short* __restrict__ oq, unsigned short* __restrict__ ok,
    unsigned short* __restrict__ ov)
{
    const int tid = threadIdx.x;
    const int lin = blockIdx.y * gridDim.x + blockIdx.x;
    const int vb  = (lin & 7) * 375 + (lin >> 3);
    const int n0 = (vb % 12) * 128;   // 0..1535
    const int m0 = (vb / 12) * 128;
    const int lane = tid & 63, wid = tid >> 6;
    const int wm = (wid & 1) * 64, wn = (wid >> 1) * 64;

    __shared__ __align__(16) unsigned short sm[24576];
    __shared__ int cids[128];
    auto As = [&](int buf) { return (unsigned short(*)[32])(sm + buf * 4096); };
    auto Ws = [&](int buf) { return (unsigned short(*)[32])(sm + 12288 + buf * 4096); };
    auto bounce = (unsigned short(*)[136])sm;

    f32x4 acc[4][4];
#pragma unroll
    for (int i = 0; i < 4; ++i)
#pragma unroll
        for (int j = 0; j < 4; ++j) acc[i][j] = (f32x4){0.f, 0.f, 0.f, 0.f};

    const unsigned short* gA0 = &A[(size_t)(m0 + wid * 16 + (lane >> 2)) * EDIM + (lane & 3) * 8];
    const unsigned short* gA1 = gA0 + (size_t)64 * EDIM;
    const unsigned short* gW0 = &Wqkv[(size_t)(n0 + wid * 16 + (lane >> 2)) * EDIM + (lane & 3) * 8];
    const unsigned short* gW1 = gW0 + (size_t)64 * EDIM;
    const int frow = lane & 15, fk = (lane >> 4) * 8;

    auto stage = [&](int buf, int k0) {
        gload16(gA0 + k0, &As(buf)[wid * 16][0]);
        gload16(gA1 + k0, &As(buf)[64 + wid * 16][0]);
        gload16(gW0 + k0, &Ws(buf)[wid * 16][0]);
        gload16(gW1 + k0, &Ws(buf)[64 + wid * 16][0]);
    };
    stage(0, 0);
    stage(1, 32);

    const int nst = EDIM / 32;   // 8
    for (int t = 0; t < nst; ++t) {
        const int cur = t % 3;
        if (t < nst - 1) asm volatile("s_waitcnt vmcnt(4)" ::: "memory");
        else             asm volatile("s_waitcnt vmcnt(0)" ::: "memory");
        __builtin_amdgcn_s_barrier();
        __builtin_amdgcn_sched_barrier(0);
        short8 af[4], wf[4];
#pragma unroll
        for (int mi = 0; mi < 4; ++mi)
            af[mi] = *(const short8*)&As(cur)[wm + mi * 16 + frow][fk];
#pragma unroll
        for (int ni = 0; ni < 4; ++ni)
            wf[ni] = *(const short8*)&Ws(cur)[wn + ni * 16 + frow][fk];
#pragma unroll
        for (int mi = 0; mi < 4; ++mi)
#pragma unroll
            for (int ni = 0; ni < 4; ++ni)
                acc[mi][ni] = __builtin_amdgcn_mfma_f32_16x16x32_bf16(
                    af[mi], wf[ni], acc[mi][ni], 0, 0, 0);
        if (t + 2 < nst) stage((t + 2) % 3, (t + 2) * 32);
    }

    // ---- epilogue: bounce through LDS for coalesced stores ----
    const int z = n0 >> 9;               // 0=q 1=k 2=v
    const int b0 = m0 / NROWS;
    const int split = (b0 + 1) * NROWS;
    const int b1 = (split <= m0 + 127) ? b0 + 1 : b0;
    float ub0[4], ub1[4];
#pragma unroll
    for (int ni = 0; ni < 4; ++ni) {
        const int np = n0 + wn + ni * 16 + frow;
        ub0[ni] = uball[(size_t)b0 * NQKV + np];
        ub1[ni] = uball[(size_t)b1 * NQKV + np];
    }
    __syncthreads();
    if (z != 0 && tid < 128) {
        const int m = m0 + tid;
        const int b = (m >= split) ? b1 : b0;
        cids[tid] = cidx[b * 512 + (m - b * NROWS + 1)];
    }
#pragma unroll
    for (int mi = 0; mi < 4; ++mi)
#pragma unroll
        for (int r = 0; r < 4; ++r) {
            const int ml = wm + mi * 16 + (lane >> 4) * 4 + r;
            const bool hi = (m0 + ml >= split);
#pragma unroll
            for (int ni = 0; ni < 4; ++ni)
                bounce[ml][wn + ni * 16 + frow] =
                    f2bf(acc[mi][ni][r] + (hi ? ub1[ni] : ub0[ni]));
        }
    __syncthreads();

    const int h0 = (n0 & 511) >> 6;
    if (z == 0) {
        const int row = tid >> 1, half = tid & 1;
        const int m = m0 + row;
        const int b = (m >= split) ? b1 : b0;
        const int l = m - b * NROWS + 1;
        unsigned short* dst = &oq[(((size_t)b * HEADS + h0 + half) * LFULL + l) * HD];
        const unsigned short* src = &bounce[row][half * 64];
#pragma unroll
        for (int j = 0; j < 8; ++j)
            *(uint4*)(dst + j * 8) = *(const uint4*)(src + j * 8);
    } else if (z == 1) {
        const int row = tid >> 1, half = tid & 1;
        const int c = cids[row];
        if (c >= 0) {
            const int m = m0 + row;
            const int b = (m >= split) ? b1 : b0;
            unsigned short* dst = &ok[(((size_t)b * HEADS + h0 + half) * CMAX + c) * HD];
            const unsigned short* src = &bounce[row][half * 64];
#pragma unroll
            for (int j = 0; j < 8; ++j)
                *(uint4*)(dst + j * 8) = *(const uint4*)(src + j * 8);
        }
    } else {
        const int col = tid & 127, mh = tid >> 7;
        const int hh = h0 + (col >> 6), dd = col & 63;
        for (int mm = 0; mm < 64; ++mm) {
            const int row = mh * 64 + mm;
            const int c = cids[row];
            if (c >= 0) {
                const int m = m0 + row;
                const int b = (m >= split) ? b1 : b0;
                ov[((size_t)b * HEADS + hh) * (size_t)(HD * CMAX)
                   + (size_t)dd * CMAX + c] = bounce[row][col];
            }
        }
    }
}

// ---------------------------------------------------------------------------
// Generic bf16 GEMM (counted-vmcnt 3-buffer) + XCD swizzle (1000 = 8 x 125).
// MODE 1 (Wo): +bias, bf16 out, per-row partial (sum f, sum f^2) -> rowpart.
// MODE 2 (W1g): LN-folded gelu + W2 dot -> 8 partials/row.
// ---------------------------------------------------------------------------
template <int MODE>
__global__ __launch_bounds__(256) void gemm_bf16(
    const unsigned short* __restrict__ A,
    const unsigned short* __restrict__ W,
    const float* __restrict__ bias, void* __restrict__ outp,
    const float* __restrict__ W2, float* __restrict__ part,
    const float2* __restrict__ musr, const float2* __restrict__ c1c2)
{
    const int tid = threadIdx.x;
    const int lin = blockIdx.y * gridDim.x + blockIdx.x;
    const int vb  = (lin & 7) * 125 + (lin >> 3);
    const int n0 = (vb % 4) * 128;
    const int m0 = (vb / 4) * 128;
    const int lane = tid & 63, wid = tid >> 6;
    const int wm = (wid & 1) * 64, wn = (wid >> 1) * 64;

    __shared__ unsigned short As[3][128][32];
    __shared__ unsigned short Ws[3][128][32];

    f32x4 acc[4][4];
#pragma unroll
    for (int i = 0; i < 4; ++i)
#pragma unroll
        for (int j = 0; j < 4; ++j) acc[i][j] = (f32x4){0.f, 0.f, 0.f, 0.f};

    const unsigned short* gA0 = &A[(size_t)(m0 + wid * 16 + (lane >> 2)) * DDIM + (lane & 3) * 8];
    const unsigned short* gA1 = gA0 + (size_t)64 * DDIM;
    const unsigned short* gW0 = &W[(size_t)(n0 + wid * 16 + (lane >> 2)) * DDIM + (lane & 3) * 8];
    const unsigned short* gW1 = gW0 + (size_t)64 * DDIM;
    const int frow = lane & 15, fk = (lane >> 4) * 8;

    auto stage = [&](int buf, int k0) {
        gload16(gA0 + k0, &As[buf][wid * 16][0]);
        gload16(gA1 + k0, &As[buf][64 + wid * 16][0]);
        gload16(gW0 + k0, &Ws[buf][wid * 16][0]);
        gload16(gW1 + k0, &Ws[buf][64 + wid * 16][0]);
    };
    stage(0, 0);
    stage(1, 32);

    const int nst = DDIM / 32;   // 16
    for (int t = 0; t < nst; ++t) {
        const int cur = t % 3;
        if (t < nst - 1) asm volatile("s_waitcnt vmcnt(4)" ::: "memory");
        else             asm volatile("s_waitcnt vmcnt(0)" ::: "memory");
        __builtin_amdgcn_s_barrier();
        __builtin_amdgcn_sched_barrier(0);
        short8 af[4], wf[4];
#pragma unroll
        for (int mi = 0; mi < 4; ++mi)
            af[mi] = *(const short8*)&As[cur][wm + mi * 16 + frow][fk];
#pragma unroll
        for (int ni = 0; ni < 4; ++ni)
            wf[ni] = *(const short8*)&Ws[cur][wn + ni * 16 + frow][fk];
#pragma unroll
        for (int mi = 0; mi < 4; ++mi)
#pragma unroll
            for (int ni = 0; ni < 4; ++ni)
                acc[mi][ni] = __builtin_amdgcn_mfma_f32_16x16x32_bf16(
                    af[mi], wf[ni], acc[mi][ni], 0, 0, 0);
        if (t + 2 < nst) stage((t + 2) % 3, (t + 2) * 32);
    }

    const int slot = (n0 >> 7) * 2 + (wn >> 6);   // 0..7
    if (MODE == 1) {
        float bv4[4];
#pragma unroll
        for (int ni = 0; ni < 4; ++ni) bv4[ni] = bias[n0 + wn + ni * 16 + frow];
#pragma unroll
        for (int mi = 0; mi < 4; ++mi)
#pragma unroll
            for (int r = 0; r < 4; ++r) {
                const int m = m0 + wm + mi * 16 + (lane >> 4) * 4 + r;
                float s1 = 0.f, s2 = 0.f;
#pragma unroll
                for (int ni = 0; ni < 4; ++ni) {
                    const float v = acc[mi][ni][r] + bv4[ni];
                    s1 += v; s2 += v * v;
                    ((unsigned short*)outp)[(size_t)m * DDIM + n0 + wn + ni * 16 + frow]
                        = f2bf(v);
                }
                s1 += __shfl_xor(s1, 1, 64); s2 += __shfl_xor(s2, 1, 64);
                s1 += __shfl_xor(s1, 2, 64); s2 += __shfl_xor(s2, 2, 64);
                s1 += __shfl_xor(s1, 4, 64); s2 += __shfl_xor(s2, 4, 64);
                s1 += __shfl_xor(s1, 8, 64); s2 += __shfl_xor(s2, 8, 64);
                if (frow == 0) {
                    part[((size_t)m << 4) + slot * 2]     = s1;
                    part[((size_t)m << 4) + slot * 2 + 1] = s2;
                }
            }
    } else {
        float w2v[4], cb[4], c2v[4];
#pragma unroll
        for (int ni = 0; ni < 4; ++ni) {
            const int n = n0 + wn + ni * 16 + frow;
            w2v[ni] = W2[n];
            const float2 cc = c1c2[n];
            cb[ni]  = cc.x + bias[n];
            c2v[ni] = cc.y;
        }
#pragma unroll
        for (int mi = 0; mi < 4; ++mi)
#pragma unroll
            for (int r = 0; r < 4; ++r) {
                const int m = m0 + wm + mi * 16 + (lane >> 4) * 4 + r;
                const float2 ms = musr[m];   // (mu, rs)
                float s = 0.f;
#pragma unroll
                for (int ni = 0; ni < 4; ++ni)
                    s += gelu_exact(ms.y * (acc[mi][ni][r] - ms.x * c2v[ni]) + cb[ni])
                         * w2v[ni];
                s += __shfl_xor(s, 1, 64);
                s += __shfl_xor(s, 2, 64);
                s += __shfl_xor(s, 4, 64);
                s += __shfl_xor(s, 8, 64);
                if (frow == 0)
                    part[(size_t)m * 8 + slot] = s;
            }
    }
}

// ---------------------------------------------------------------------------
// lnstats: fold 16 partials -> (mu, rs) per row.
// ---------------------------------------------------------------------------
__global__ __launch_bounds__(256) void lnstats_kernel(
    const float* __restrict__ rowpart, float2* __restrict__ musr)
{
    const int m = blockIdx.x * 256 + threadIdx.x;
    if (m >= MTOT) return;
    const float* p = rowpart + ((size_t)m << 4);
    float s1 = 0.f, s2 = 0.f;
#pragma unroll
    for (int i = 0; i < 8; ++i) { s1 += p[i * 2]; s2 += p[i * 2 + 1]; }
    const float mu = s1 * (1.0f / DDIM);
    const float var = s2 * (1.0f / DDIM) - mu * mu;
    musr[m] = make_float2(mu, rsqrtf(var + 1e-5f));
}

// ---------------------------------------------------------------------------
// Final reduction: out[m] = b2 + sum of 8 partials.
// ---------------------------------------------------------------------------
__global__ __launch_bounds__(256) void w2red_kernel(
    const float* __restrict__ part, const float* __restrict__ b2,
    float* __restrict__ out)
{
    const int m = blockIdx.x * 256 + threadIdx.x;
    if (m >= MTOT) return;
    const float* p = part + (size_t)m * 8;
    float s = b2[0];
#pragma unroll
    for (int i = 0; i < 8; ++i) s += p[i];
    out[m] = s;
}

// ---------------------------------------------------------------------------
// Attention v7: row-packed 32-row blocks, per-row key-count mask, fused exp,
// XCD-chunked swizzle (8192 = 8 x 1024).
// ---------------------------------------------------------------------------
__global__ __launch_bounds__(256) void attn_mfma(
    const unsigned short* __restrict__ qx, const unsigned short* __restrict__ kc,
    const unsigned short* __restrict__ vc, const int* __restrict__ cnt,
    unsigned short* __restrict__ outb)
{
    const int lin = blockIdx.x + NRB * (blockIdx.y + HEADS * blockIdx.z);
    const int vbk = (lin & 7) * (NRB * HEADS * BATCH / 8) + (lin >> 3);
    const int rbk = vbk % NRB;
    const int h   = (vbk / NRB) % HEADS;
    const int b   = vbk / (NRB * HEADS);
    const int g0  = rbk * RB;

    const int tid = threadIdx.x, lane = tid & 63, w = tid >> 6;

    __shared__ __align__(16) unsigned short scb[RB][520];
    __shared__ float rsw[4][RB];
    __shared__ int snck[RB];

    const int frow = lane & 15, fk = (lane >> 4) * 8;
    const size_t bh = (size_t)b * HEADS + h;
    const unsigned short* kbase = kc + bh * (CMAX * HD);
    const unsigned short* vbase = vc + bh * (HD * CMAX);

    if (tid < RB) {
        const int s = (g0 + tid >= NROWS ? NROWS - 1 : g0 + tid) / KPS;
        snck[tid] = cnt[b * 32 + s];
    }

    short8 qf[2][2];
#pragma unroll
    for (int mi = 0; mi < 2; ++mi) {
        const int qrow = g0 + mi * 16 + frow;
#pragma unroll
        for (int ks = 0; ks < 2; ++ks) {
            short8 v = {};
            if (qrow < NROWS)
                v = *(const short8*)&qx[(bh * LFULL + qrow + 1) * HD + ks * 32 + fk];
            qf[mi][ks] = v;
        }
    }
    __syncthreads();

    int nck8[2][4];
#pragma unroll
    for (int mi = 0; mi < 2; ++mi)
#pragma unroll
        for (int r = 0; r < 4; ++r)
            nck8[mi][r] = snck[mi * 16 + (lane >> 4) * 4 + r];
    const int nmax = snck[RB - 1];
    const int NT = (nmax + 63) >> 6;

    f32x4 rsum[2];
    rsum[0] = (f32x4){0.f, 0.f, 0.f, 0.f};
    rsum[1] = (f32x4){0.f, 0.f, 0.f, 0.f};
    for (int t = 0; t < NT; ++t) {
        const int key = (t << 6) + w * 16 + frow;
        const unsigned short* kr = kbase + (size_t)key * HD;
        const short8 kf0 = *(const short8*)(kr + fk);
        const short8 kf1 = *(const short8*)(kr + 32 + fk);
        f32x4 s2[2];
#pragma unroll
        for (int mi = 0; mi < 2; ++mi) {
            s2[mi] = (f32x4){0.f, 0.f, 0.f, 0.f};
            s2[mi] = __builtin_amdgcn_mfma_f32_16x16x32_bf16(qf[mi][0], kf0, s2[mi], 0, 0, 0);
            s2[mi] = __builtin_amdgcn_mfma_f32_16x16x32_bf16(qf[mi][1], kf1, s2[mi], 0, 0, 0);
        }
#pragma unroll
        for (int mi = 0; mi < 2; ++mi)
#pragma unroll
            for (int r = 0; r < 4; ++r) {
                const int row = mi * 16 + (lane >> 4) * 4 + r;
                const float p = (key < nck8[mi][r]) ? __expf(s2[mi][r] * 0.125f) : 0.f;
                rsum[mi][r] += p;
                scb[row][key] = f2bf(p);
            }
    }
#pragma unroll
    for (int mi = 0; mi < 2; ++mi)
#pragma unroll
        for (int r = 0; r < 4; ++r) {
            float v = rsum[mi][r];
            v += __shfl_xor(v, 1, 64);
            v += __shfl_xor(v, 2, 64);
            v += __shfl_xor(v, 4, 64);
            v += __shfl_xor(v, 8, 64);
            if (frow == 0)
                rsw[w][mi * 16 + (lane >> 4) * 4 + r] = v;
        }
    __syncthreads();

    f32x4 po[2];
    po[0] = (f32x4){0.f, 0.f, 0.f, 0.f};
    po[1] = (f32x4){0.f, 0.f, 0.f, 0.f};
    const unsigned short* vrow = vbase + (size_t)(w * 16 + frow) * CMAX;
    for (int t = 0; t < NT; ++t) {
#pragma unroll
        for (int ks = 0; ks < 2; ++ks) {
            const int kb0 = (t << 6) + ks * 32 + fk;
            const short8 vf = *(const short8*)(vrow + kb0);
#pragma unroll
            for (int mi = 0; mi < 2; ++mi) {
                const short8 pf = *(const short8*)&scb[mi * 16 + frow][kb0];
                po[mi] = __builtin_amdgcn_mfma_f32_16x16x32_bf16(pf, vf, po[mi], 0, 0, 0);
            }
        }
    }

#pragma unroll
    for (int mi = 0; mi < 2; ++mi)
#pragma unroll
        for (int r = 0; r < 4; ++r) {
            const int row = mi * 16 + (lane >> 4) * 4 + r;
            const int m = g0 + row;
            if (m < NROWS) {
                const float inv = 1.0f / (rsw[0][row] + rsw[1][row]
                                        + rsw[2][row] + rsw[3][row]);
                outb[((size_t)b * NROWS + m) * DDIM
                     + h * HD + w * 16 + frow] = f2bf(po[mi][r] * inv);
            }
        }
}

// ---------------------------------------------------------------------------
extern "C" void kernel_launch(void* const* d_in, const int* in_sizes, int n_in,
                              void* d_out, int out_size, void* d_ws, size_t ws_size,
                              hipStream_t stream)
{
    const float* item = (const float*)d_in[0];
    const float* user = (const float*)d_in[1];
    const int*   resp = (const int*)d_in[2];
    const float* Wq = (const float*)d_in[3];  const float* bq = (const float*)d_in[4];
    const float* Wk = (const float*)d_in[5];  const float* bk = (const float*)d_in[6];
    const float* Wv = (const float*)d_in[7];  const float* bv = (const float*)d_in[8];
    const float* Wo = (const float*)d_in[9];  const float* bo = (const float*)d_in[10];
    const float* lng = (const float*)d_in[11]; const float* lnb = (const float*)d_in[12];
    const float* W1 = (const float*)d_in[13]; const float* b1 = (const float*)d_in[14];
    const float* W2 = (const float*)d_in[15]; const float* b2 = (const float*)d_in[16];
    float* out = (float*)d_out;

    char* p = (char*)d_ws;
    auto alloc = [&](size_t bytes) { char* r = p; p += (bytes + 255) & ~(size_t)255; return r; };
    const size_t NITEM = (size_t)BATCH * NROWS * EDIM;
    const size_t NW    = (size_t)DDIM * DDIM;
    const size_t NQ    = (size_t)BATCH * HEADS * LFULL * HD;
    const size_t NC    = (size_t)BATCH * HEADS * CMAX * HD;
    const size_t NMD   = (size_t)MTOT * DDIM;
    const size_t PAD   = 8192;

    unsigned short* itemb  = (unsigned short*)alloc(NITEM * 2);
    unsigned short* Wqkvb  = (unsigned short*)alloc((size_t)NQKV * EDIM * 2);
    unsigned short* Wob    = (unsigned short*)alloc(NW * 2);
    unsigned short* W1gb   = (unsigned short*)alloc(NW * 2);
    unsigned short* qb     = (unsigned short*)alloc(NQ * 2 + PAD);
    unsigned short* kcb    = (unsigned short*)alloc(NC * 2 + PAD);
    unsigned short* vcb    = (unsigned short*)alloc(NC * 2 + PAD);
    unsigned short* aob    = (unsigned short*)alloc(NMD * 2);
    unsigned short* fb16   = (unsigned short*)alloc(NMD * 2);
    float*  uball  = (float*)alloc((size_t)BATCH * NQKV * 4);
    float*  part   = (float*)alloc((size_t)MTOT * 8 * 4);
    float*  rowpart= (float*)alloc((size_t)MTOT * 16 * 4);
    float2* musr   = (float2*)alloc((size_t)MTOT * 8);
    float2* c1c2   = (float2*)alloc((size_t)DDIM * 8);
    int* cidx    = (int*)alloc((size_t)BATCH * 512 * 4);
    int* cnt     = (int*)alloc((size_t)BATCH * 32 * 4);

    cvt_kernel<<<dim3((NITEM / 4 + 255) / 256), 256, 0, stream>>>(item, itemb, NITEM / 4);
    packqkv_kernel<<<dim3(DDIM * EDIM / 4 / 256, 3), 256, 0, stream>>>(Wq, Wk, Wv, Wqkvb);
    cvt_kernel<<<dim3(NW / 4 / 256), 256, 0, stream>>>(Wo, Wob, NW / 4);
    w1prep_kernel<<<dim3(DDIM / 4), 256, 0, stream>>>(W1, lng, lnb, W1gb, c1c2);

    compact_kernel<<<dim3(BATCH), 64, 0, stream>>>(resp, cidx, cnt);

    user_bias_kernel<<<dim3(BATCH, 3), 256, 0, stream>>>(
        user, Wq, bq, Wk, bk, Wv, bv, uball, qb, kcb, vcb);

    gemm_qkv<<<dim3(NQKV / 128, MTOT / 128), 256, 0, stream>>>(
        itemb, Wqkvb, uball, cidx, qb, kcb, vcb);

    attn_mfma<<<dim3(NRB, HEADS, BATCH), 256, 0, stream>>>(qb, kcb, vcb, cnt, aob);

    dim3 gg(DDIM / 128, MTOT / 128);
    // f = ao @ Wo^T + bo (bf16) + per-row LN partial sums
    gemm_bf16<1><<<gg, 256, 0, stream>>>(aob, Wob, bo, fb16, nullptr, rowpart,
                                         nullptr, nullptr);
    lnstats_kernel<<<dim3((MTOT + 255) / 256), 256, 0, stream>>>(rowpart, musr);
    // h partials = gelu(LN-folded f @ W1g^T) . W2
    gemm_bf16<2><<<gg, 256, 0, stream>>>(fb16, W1gb, b1, nullptr, W2, part,
                                         musr, c1c2);
    w2red_kernel<<<dim3((MTOT + 255) / 256), 256, 0, stream>>>(part, b2, out);
}